// Round 11
// baseline (685.370 us; speedup 1.0000x reference)
//
#include <hip/hip_runtime.h>
#include <stdint.h>

#define PTOT 2784
#define PM1  2783
#define DDIM 1408
#define NB   8
#define ROWS 22272        // NB*PTOT
#define KHEAD 2816        // 2*DDIM
#define MROW 2816         // Mbf8 rows per batch, row stride 2816 B
#define BTROWS 1536       // bafT8 rows per batch, row stride 2816 B

typedef __attribute__((ext_vector_type(8))) short bf16x8;
typedef __attribute__((ext_vector_type(4))) float f32x4;
typedef long i64f8;       // 8 x fp8 fragment

__device__ __forceinline__ short f2bf_rne(float x) {
    uint32_t u = __float_as_uint(x);
    u += 0x7fffu + ((u >> 16) & 1u);
    return (short)(u >> 16);
}
__device__ __forceinline__ float bf2f(short s) {
    return __uint_as_float((uint32_t)(unsigned short)s << 16);
}

// f32 -> OCP e4m3fn, RNE, saturate at 448, flush |x|<2^-6 to 0
__device__ __forceinline__ unsigned char f2e4m3(float x) {
    uint32_t u = __float_as_uint(x);
    uint32_t sgn = (u >> 24) & 0x80u;
    uint32_t ax = u & 0x7fffffffu;
    ax += 0x7ffffu + ((ax >> 20) & 1u);          // RNE at 3 mantissa bits
    if (ax >= 0x43E80000u) return (unsigned char)(sgn | 0x7Eu);  // sat 448
    if (ax < 0x3C800000u) return (unsigned char)sgn;             // flush
    uint32_t e = (ax >> 23) - 120u;
    uint32_t m = (ax >> 20) & 7u;
    return (unsigned char)(sgn | (e << 3) | m);
}

// async global->LDS, 16B per lane. lds dest = wave-uniform base + lane*16.
__device__ __forceinline__ void gld16(const void* g, void* l) {
    __builtin_amdgcn_global_load_lds(
        (const __attribute__((address_space(1))) void*)(uintptr_t)g,
        (__attribute__((address_space(3))) void*)(uint32_t)(uintptr_t)l,
        16, 0, 0);
}

#define VMW(N) asm volatile("s_waitcnt vmcnt(" #N ")" ::: "memory")

// ---------------- kernel 1: 1x1 conv -> feat (f32, written to d_out) ----------
__global__ __launch_bounds__(256) void k_conv(
    const float* __restrict__ x, const float* __restrict__ w,
    const float* __restrict__ cb, float* __restrict__ feat) {
  __shared__ float xs[256 * 32];
  int b = blockIdx.x / 28;
  int t0 = (blockIdx.x % 28) * 32;
  int t = threadIdx.x;
  for (int i = t; i < 256 * 32; i += 256) {
    int c = i >> 5, pos = i & 31;
    int hw = t0 + pos;
    xs[i] = (hw < 880) ? x[((size_t)b * 256 + c) * 880 + hw] : 0.f;
  }
  __syncthreads();
  int o = t & 63, g = t >> 6;
  float acc[8];
#pragma unroll
  for (int pp = 0; pp < 8; ++pp) acc[pp] = cb[o];
  const float* wr = w + o * 256;
  for (int c = 0; c < 256; ++c) {
    float wv = wr[c];
#pragma unroll
    for (int pp = 0; pp < 8; ++pp) acc[pp] += wv * xs[c * 32 + g + pp * 4];
  }
#pragma unroll
  for (int pp = 0; pp < 8; ++pp) {
    int hw = t0 + g + pp * 4;
    if (hw < 880) feat[((size_t)b * 64 + o) * 880 + hw] = acc[pp];
  }
}

// ------- kernel 2: prep (bf16 weights, bias, diag seeds, fp8 pad zeroing) -----
__global__ __launch_bounds__(256) void k_prep(
    const float* __restrict__ att_w, const float* __restrict__ cls_w,
    const float* __restrict__ so_w, const float* __restrict__ reg_w,
    const float* __restrict__ cls_b, const float* __restrict__ so_b,
    const float* __restrict__ reg_b,
    short* __restrict__ attw, short* __restrict__ wbf,
    float* __restrict__ bias80, float* __restrict__ M,
    unsigned char* __restrict__ Mbf8, unsigned char* __restrict__ bafT8,
    short* __restrict__ Msc) {
  const int64_t n_attw = (int64_t)2816 * DDIM;
  const int64_t n_w = 80 * (int64_t)KHEAD;
  const int64_t n_pa = (int64_t)NB * MROW * 32;    // Mbf8 pad cols [2784,2816)
  const int64_t n_pb = (int64_t)NB * BTROWS * 32;  // bafT8 pad cols
  const int64_t total = n_attw + n_w + 80 + ROWS + n_pa + n_pb;
  for (int64_t i = (int64_t)blockIdx.x * 256 + threadIdx.x; i < total;
       i += (int64_t)gridDim.x * 256) {
    if (i < n_attw) {
      int j = (int)(i / DDIM), k = (int)(i - (int64_t)j * DDIM);
      float v = (j < PM1) ? att_w[(size_t)j * DDIM + k] : 0.f;
      attw[i] = f2bf_rne(v);
    } else if (i < n_attw + n_w) {
      int64_t ii = i - n_attw;
      int n = (int)(ii / KHEAD), k = (int)(ii - (int64_t)n * KHEAD);
      float v = 0.f;
      if (n < 2) v = cls_w[n * KHEAD + k];
      else if (n == 2) v = so_w[k];
      else if (n < 76) v = reg_w[(size_t)(n - 3) * KHEAD + k];
      wbf[ii] = f2bf_rne(v);
    } else if (i < n_attw + n_w + 80) {
      int n = (int)(i - n_attw - n_w);
      float v = 0.f;
      if (n < 2) v = cls_b[n];
      else if (n == 2) v = so_b[0];
      else if (n < 76) v = reg_b[n - 3];
      bias80[n] = v;
    } else if (i < n_attw + n_w + 80 + ROWS) {
      int r = (int)(i - n_attw - n_w - 80);
      int p = r % PTOT;
      M[(size_t)r * PTOT + p] = -1e30f;            // fallback path diag
      if (Msc) Msc[(size_t)r * PTOT + p] = f2bf_rne(-1e30f);  // fast path diag
    } else if (i < n_attw + n_w + 80 + ROWS + n_pa) {
      int64_t ii = i - n_attw - n_w - 80 - ROWS;
      int64_t row = ii >> 5; int c = (int)(ii & 31);
      Mbf8[row * 2816 + 2784 + c] = 0;
    } else {
      int64_t ii = i - n_attw - n_w - 80 - ROWS - n_pa;
      int64_t row = ii >> 5; int c = (int)(ii & 31);
      bafT8[row * 2816 + 2784 + c] = 0;
    }
  }
}

// ---------------- kernel 3: gather rois -> baf bf16 + bafT8 fp8 ---------------
__global__ __launch_bounds__(256) void k_gather(
    const float* __restrict__ feat, const int* __restrict__ cutx,
    const unsigned char* __restrict__ inval,
    short* __restrict__ baf, unsigned char* __restrict__ bafT8) {
  int p0 = blockIdx.x * 64, d0 = blockIdx.y * 64, b = blockIdx.z;
  __shared__ short tile[64][72];
  int t = threadIdx.x;
  for (int i = t; i < 64 * 64; i += 256) {
    int pl = i >> 6, dl = i & 63;
    int p = p0 + pl, d = d0 + dl;
    float v = 0.f;
    if (p < PTOT && d < DDIM) {
      int c = d / 22, h = d - c * 22;
      if (!inval[p * 22 + h]) {
        int xc = cutx[p * 22 + h];
        v = feat[(((size_t)b * 64 + c) * 22 + h) * 40 + xc];
      }
    }
    tile[pl][dl] = f2bf_rne(v);
  }
  __syncthreads();
  if (d0 < DDIM) {
    for (int u = t; u < 512; u += 256) {   // baf rows: coalesced along d
      int pl = u >> 3, dg = u & 7;
      int p = p0 + pl;
      if (p < PTOT) {
        bf16x8 v;
#pragma unroll
        for (int e = 0; e < 8; ++e) v[e] = tile[pl][dg * 8 + e];
        *(bf16x8*)&baf[((size_t)b * PTOT + p) * DDIM + d0 + dg * 8] = v;
      }
    }
  }
  for (int u = t; u < 512; u += 256) {     // bafT8 rows: fp8, stride 2816
    int dl = u >> 3, pg = u & 7;
    int pbase = p0 + pg * 8;
    if (pbase + 7 < PTOT) {
      unsigned long long pk = 0;
#pragma unroll
      for (int e = 0; e < 8; ++e) {
        float fv = bf2f(tile[pg * 8 + e][dl]);
        pk |= (unsigned long long)f2e4m3(fv) << (8 * e);
      }
      *(unsigned long long*)&bafT8[((size_t)b * BTROWS + d0 + dl) * 2816 + pbase] = pk;
    }
  }
}

// =========== scores: 128x128 4-wave bf16, 3-slot STATIC pipeline ==============
// 48KB LDS, depth-2 prefetch, vmcnt(8/4/0), raw s_barrier. Slots are
// COMPILE-TIME (steady loop unrolled x3: 42 = 3*14) so every LDS address
// const-folds -- R10's runtime slot rotation cost +20% VALUBusy.
// Slot s rewritten by stage(t+3) one barrier after its readers finished.
#define SC_TILE(OFF_, S_, SN_, STAGE_, VM_)                                    \
  {                                                                            \
    const char* cb_ = sm + (S_) * 16384;                                       \
    if (STAGE_) {                                                              \
      char* nb_ = sm + (SN_) * 16384;                                          \
      gld16(gA0 + (OFF_), nb_ + dd0);                                          \
      gld16(gA1 + (OFF_), nb_ + dd1);                                          \
      gld16(gB0 + (OFF_), nb_ + 8192 + dd0);                                   \
      gld16(gB1 + (OFF_), nb_ + 8192 + dd1);                                   \
    }                                                                          \
    if ((VM_) == 8) VMW(8); else if ((VM_) == 4) VMW(4); else VMW(0);          \
    __builtin_amdgcn_s_barrier();                                              \
    bf16x8 av[4], bv[4];                                                       \
    _Pragma("unroll") for (int i = 0; i < 4; ++i)                              \
      av[i] = *(const bf16x8*)(cb_ + offA[i]);                                 \
    _Pragma("unroll") for (int i = 0; i < 4; ++i)                              \
      bv[i] = *(const bf16x8*)(cb_ + 8192 + offB[i]);                          \
    _Pragma("unroll") for (int mi = 0; mi < 4; ++mi)                           \
      _Pragma("unroll") for (int ni = 0; ni < 4; ++ni)                         \
        acc[mi][ni] = __builtin_amdgcn_mfma_f32_16x16x32_bf16(                 \
            av[mi], bv[ni], acc[mi][ni], 0, 0, 0);                             \
    __builtin_amdgcn_s_barrier();                                              \
  }

template<int OUTMODE>
__global__ __launch_bounds__(256) void k_scores(
    const short* __restrict__ baf, const short* __restrict__ attw,
    const float* __restrict__ att_b, float* __restrict__ Mout,
    short* __restrict__ Msc) {
  __shared__ char sm[49152];
  int wg = blockIdx.x;                       // 3828 = 174*22; q=478 r=4
  int xcd = wg & 7, lin = wg >> 3;
  int wgid = (xcd < 4) ? xcd * 479 + lin : 1916 + (xcd - 4) * 478 + lin;
  int it = wgid / 22, nt = wgid - it * 22;
  int m0 = it * 128, n0 = nt * 128;

  int t = threadIdx.x, w = t >> 6, l = t & 63;
  int lr = l & 15, lg = l >> 4;
  int wr = w >> 1, wc = w & 1;

  const char* gA0; const char* gA1; const char* gB0; const char* gB1;
  int dd0, dd1;
  {
    int o0 = w * 2048 + l * 16;
    int o1 = o0 + 1024;
    int r0_ = o0 >> 6, c0 = (o0 & 63) ^ (((o0 >> 7) & 3) << 4);
    int r1_ = o1 >> 6, c1 = (o1 & 63) ^ (((o1 >> 7) & 3) << 4);
    gA0 = (const char*)(baf + (size_t)(m0 + r0_) * DDIM) + c0;
    gA1 = (const char*)(baf + (size_t)(m0 + r1_) * DDIM) + c1;
    gB0 = (const char*)(attw + (size_t)(n0 + r0_) * DDIM) + c0;
    gB1 = (const char*)(attw + (size_t)(n0 + r1_) * DDIM) + c1;
    dd0 = o0; dd1 = o1;
  }
  int offA[4], offB[4];
#pragma unroll
  for (int i = 0; i < 4; ++i) {
    int xa = (wr * 64 + i * 16 + lr) * 64 + lg * 16;
    offA[i] = xa ^ (((xa >> 7) & 3) << 4);
    int xb = (wc * 64 + i * 16 + lr) * 64 + lg * 16;
    offB[i] = xb ^ (((xb >> 7) & 3) << 4);
  }

  f32x4 acc[4][4];
  const f32x4 fz = {0.f, 0.f, 0.f, 0.f};
#pragma unroll
  for (int mi = 0; mi < 4; ++mi)
#pragma unroll
    for (int ni = 0; ni < 4; ++ni) acc[mi][ni] = fz;

  // prologue: stage tiles 0,1 into slots 0,1
  gld16(gA0, sm + dd0);            gld16(gA1, sm + dd1);
  gld16(gB0, sm + 8192 + dd0);     gld16(gB1, sm + 8192 + dd1);
  gld16(gA0 + 64, sm + 16384 + dd0);        gld16(gA1 + 64, sm + 16384 + dd1);
  gld16(gB0 + 64, sm + 16384 + 8192 + dd0); gld16(gB1 + 64, sm + 16384 + 8192 + dd1);

  for (int q = 0; q < 14; ++q) {             // tiles 3q..3q+2, slots 0,1,2
    SC_TILE(128, 0, 2, 1, 8);
    SC_TILE(192, 1, 0, 1, 8);
    SC_TILE(256, 2, 1, 1, 8);
    gA0 += 192; gA1 += 192; gB0 += 192; gB1 += 192;
  }
  SC_TILE(0, 0, 0, 0, 4);                    // tile 42, slot 0
  SC_TILE(0, 1, 0, 0, 0);                    // tile 43, slot 1

#pragma unroll
  for (int mi = 0; mi < 4; ++mi) {
#pragma unroll
    for (int rg = 0; rg < 4; ++rg) {
      int gmi = m0 + wr * 64 + mi * 16 + lg * 4 + rg;
      int i = gmi % PTOT;
#pragma unroll
      for (int ni = 0; ni < 4; ++ni) {
        int j = n0 + wc * 64 + ni * 16 + lr;
        if (j < PM1) {
          int q2 = j + (j >= i);
          float v = acc[mi][ni][rg] + att_b[j];
          if (OUTMODE == 0) Mout[(size_t)gmi * PTOT + q2] = v;
          else              Msc[(size_t)gmi * PTOT + q2] = f2bf_rne(v);
        }
      }
    }
  }
}

// =========== attfeat: 128x128 4-wave FP8, 3-slot STATIC pipeline ==============
#define AF_TILE(OFF_, S_, SN_, STAGE_, VM_)                                    \
  {                                                                            \
    const char* cb_ = sm + (S_) * 16384;                                       \
    if (STAGE_) {                                                              \
      char* nb_ = sm + (SN_) * 16384;                                          \
      gld16(gA0 + (OFF_), nb_ + dd0);                                          \
      gld16(gA1 + (OFF_), nb_ + dd1);                                          \
      gld16(gB0 + (OFF_), nb_ + 8192 + dd0);                                   \
      gld16(gB1 + (OFF_), nb_ + 8192 + dd1);                                   \
    }                                                                          \
    if ((VM_) == 8) VMW(8); else if ((VM_) == 4) VMW(4); else VMW(0);          \
    __builtin_amdgcn_s_barrier();                                              \
    _Pragma("unroll") for (int ks = 0; ks < 2; ++ks) {                         \
      i64f8 av[4], bv[4];                                                      \
      _Pragma("unroll") for (int i = 0; i < 4; ++i)                            \
        av[i] = *(const i64f8*)(cb_ + offA[i * 2 + ks]);                       \
      _Pragma("unroll") for (int i = 0; i < 4; ++i)                            \
        bv[i] = *(const i64f8*)(cb_ + 8192 + offB[i * 2 + ks]);                \
      _Pragma("unroll") for (int mi = 0; mi < 4; ++mi)                         \
        _Pragma("unroll") for (int ni = 0; ni < 4; ++ni)                       \
          acc[mi][ni] = __builtin_amdgcn_mfma_f32_16x16x32_fp8_fp8(            \
              av[mi], bv[ni], acc[mi][ni], 0, 0, 0);                           \
    }                                                                          \
    __builtin_amdgcn_s_barrier();                                              \
  }

__global__ __launch_bounds__(256) void k_attfeat8(
    const unsigned char* __restrict__ Mbf8,
    const unsigned char* __restrict__ bafT8,
    short* __restrict__ attf) {
  __shared__ char sm[49152];
  int wg = blockIdx.x;                       // 1936 = 8 * 242
  int wgid = (wg & 7) * 242 + (wg >> 3);     // XCD-chunked, bijective
  int bb = wgid / 242;
  int rem = wgid - bb * 242;
  int it = rem / 11, nt = rem - it * 11;     // nt fastest: A-panel reuse
  int m0 = it * 128, n0 = nt * 128;
  const unsigned char* Ab = Mbf8 + ((size_t)bb * MROW + m0) * 2816;
  const unsigned char* Bb = bafT8 + ((size_t)bb * BTROWS + n0) * 2816;

  int t = threadIdx.x, w = t >> 6, l = t & 63;
  int lr = l & 15, lg = l >> 4;
  int wr = w >> 1, wc = w & 1;

  const char* gA0; const char* gA1; const char* gB0; const char* gB1;
  int dd0, dd1;
  {
    int o0 = t * 16;
    int o1 = o0 + 4096;
    int r0_ = o0 >> 6, c0 = (o0 & 63) ^ (((o0 >> 7) & 3) << 4);
    int r1_ = o1 >> 6, c1 = (o1 & 63) ^ (((o1 >> 7) & 3) << 4);
    gA0 = (const char*)Ab + (size_t)r0_ * 2816 + c0;
    gA1 = (const char*)Ab + (size_t)r1_ * 2816 + c1;
    gB0 = (const char*)Bb + (size_t)r0_ * 2816 + c0;
    gB1 = (const char*)Bb + (size_t)r1_ * 2816 + c1;
    dd0 = o0; dd1 = o1;
  }
  int offA[8], offB[8];
#pragma unroll
  for (int i = 0; i < 4; ++i) {
#pragma unroll
    for (int ks = 0; ks < 2; ++ks) {
      int xa = (wr * 64 + i * 16 + lr) * 64 + ks * 32 + lg * 8;
      offA[i * 2 + ks] = xa ^ (((xa >> 7) & 3) << 4);
      int xb = (wc * 64 + i * 16 + lr) * 64 + ks * 32 + lg * 8;
      offB[i * 2 + ks] = xb ^ (((xb >> 7) & 3) << 4);
    }
  }

  f32x4 acc[4][4];
  const f32x4 fz = {0.f, 0.f, 0.f, 0.f};
#pragma unroll
  for (int mi = 0; mi < 4; ++mi)
#pragma unroll
    for (int ni = 0; ni < 4; ++ni) acc[mi][ni] = fz;

  // prologue: stage tiles 0,1 into slots 0,1
  gld16(gA0, sm + dd0);            gld16(gA1, sm + dd1);
  gld16(gB0, sm + 8192 + dd0);     gld16(gB1, sm + 8192 + dd1);
  gld16(gA0 + 64, sm + 16384 + dd0);        gld16(gA1 + 64, sm + 16384 + dd1);
  gld16(gB0 + 64, sm + 16384 + 8192 + dd0); gld16(gB1 + 64, sm + 16384 + 8192 + dd1);

  for (int q = 0; q < 14; ++q) {
    AF_TILE(128, 0, 2, 1, 8);
    AF_TILE(192, 1, 0, 1, 8);
    AF_TILE(256, 2, 1, 1, 8);
    gA0 += 192; gA1 += 192; gB0 += 192; gB1 += 192;
  }
  AF_TILE(0, 0, 0, 0, 4);                    // tile 42
  AF_TILE(0, 1, 0, 0, 0);                    // tile 43

  const float US = 1.0f / 1024.0f;
#pragma unroll
  for (int mi = 0; mi < 4; ++mi) {
#pragma unroll
    for (int rg = 0; rg < 4; ++rg) {
      int i = m0 + wr * 64 + mi * 16 + lg * 4 + rg;
      if (i < PTOT) {
        short* arow = attf + ((size_t)(bb * PTOT + i)) * DDIM + n0 + wc * 64;
#pragma unroll
        for (int ni = 0; ni < 4; ++ni)
          arow[ni * 16 + lr] = f2bf_rne(acc[mi][ni][rg] * US);
      }
    }
  }
}

// -------- kernel 5: row softmax -> f32 M (required output) + fp8 Mbf8 ---------
template<int INMODE>
__global__ __launch_bounds__(256) void k_softmax(float* __restrict__ M,
                                                 unsigned char* __restrict__ Mbf8,
                                                 const short* __restrict__ Msc) {
  __shared__ float red[8];
  int r = blockIdx.x;
  int b = r / PTOT, p = r - b * PTOT;
  float* pr = M + (size_t)r * PTOT;
  const short* ms = INMODE ? (Msc + (size_t)r * PTOT) : (const short*)nullptr;
  unsigned char* mb = Mbf8 + ((size_t)b * MROW + p) * 2816;
  int t = threadIdx.x;
  bool has2 = (t < 348 - 256);
  float v0[8], v1[8];
  float mx = -3.0e38f;
  if (INMODE == 0) {
    f32x4 a0 = *(const f32x4*)(pr + t * 8);
    f32x4 a1 = *(const f32x4*)(pr + t * 8 + 4);
#pragma unroll
    for (int e = 0; e < 4; ++e) { v0[e] = a0[e]; v0[4 + e] = a1[e]; }
  } else {
    bf16x8 a = *(const bf16x8*)(ms + t * 8);
#pragma unroll
    for (int e = 0; e < 8; ++e) v0[e] = bf2f(a[e]);
  }
#pragma unroll
  for (int e = 0; e < 8; ++e) mx = fmaxf(mx, v0[e]);
  if (has2) {
    if (INMODE == 0) {
      f32x4 b0 = *(const f32x4*)(pr + (256 + t) * 8);
      f32x4 b1 = *(const f32x4*)(pr + (256 + t) * 8 + 4);
#pragma unroll
      for (int e = 0; e < 4; ++e) { v1[e] = b0[e]; v1[4 + e] = b1[e]; }
    } else {
      bf16x8 bb = *(const bf16x8*)(ms + (256 + t) * 8);
#pragma unroll
      for (int e = 0; e < 8; ++e) v1[e] = bf2f(bb[e]);
    }
#pragma unroll
    for (int e = 0; e < 8; ++e) mx = fmaxf(mx, v1[e]);
  }
#pragma unroll
  for (int off = 32; off; off >>= 1) mx = fmaxf(mx, __shfl_xor(mx, off));
  if ((t & 63) == 0) red[t >> 6] = mx;
  __syncthreads();
  mx = fmaxf(fmaxf(red[0], red[1]), fmaxf(red[2], red[3]));
  float s = 0.f;
#pragma unroll
  for (int e = 0; e < 8; ++e) { v0[e] = __expf(v0[e] - mx); s += v0[e]; }
  if (has2) {
#pragma unroll
    for (int e = 0; e < 8; ++e) { v1[e] = __expf(v1[e] - mx); s += v1[e]; }
  }
#pragma unroll
  for (int off = 32; off; off >>= 1) s += __shfl_xor(s, off);
  if ((t & 63) == 0) red[4 + (t >> 6)] = s;
  __syncthreads();
  s = (red[4] + red[5]) + (red[6] + red[7]);
  float inv = 1.f / s;
  float invs = inv * 1024.f;
  {
    f32x4 o0, o1; unsigned long long pk = 0;
#pragma unroll
    for (int e = 0; e < 8; ++e) {
      float wv = v0[e] * inv;
      if (e < 4) o0[e] = wv; else o1[e - 4] = wv;
      pk |= (unsigned long long)f2e4m3(v0[e] * invs) << (8 * e);
    }
    *(f32x4*)(pr + t * 8) = o0;
    *(f32x4*)(pr + t * 8 + 4) = o1;
    *(unsigned long long*)(mb + t * 8) = pk;
  }
  if (has2) {
    f32x4 o0, o1; unsigned long long pk = 0;
#pragma unroll
    for (int e = 0; e < 8; ++e) {
      float wv = v1[e] * inv;
      if (e < 4) o0[e] = wv; else o1[e - 4] = wv;
      pk |= (unsigned long long)f2e4m3(v1[e] * invs) << (8 * e);
    }
    *(f32x4*)(pr + (256 + t) * 8) = o0;
    *(f32x4*)(pr + (256 + t) * 8 + 4) = o1;
    *(unsigned long long*)(mb + (256 + t) * 8) = pk;
  }
}

// ---------------- kernel 7: heads GEMM + proposal assembly --------------------
__global__ __launch_bounds__(256) void k_head(
    const short* __restrict__ attf, const short* __restrict__ baf,
    const short* __restrict__ wbf, const float* __restrict__ bias80,
    const float* __restrict__ anch, float* __restrict__ out) {
  __shared__ short smA[64 * 32];
  __shared__ short smB[80 * 32];
  int r0 = blockIdx.x * 64;
  int t = threadIdx.x, wid = t >> 6, lane = t & 63;
  int rowa = t >> 2, kg = t & 3;
  const short* sA_att = attf + (size_t)(r0 + rowa) * DDIM + kg * 8;
  const short* sA_baf = baf + (size_t)(r0 + rowa) * DDIM + kg * 8;
  const short* sB0 = wbf + (size_t)rowa * KHEAD + kg * 8;
  const short* sB1 = wbf + (size_t)(64 + (t >> 2)) * KHEAD + (t & 3) * 8;
  char* lA = (char*)smA + wid * 1024;
  char* lB0 = (char*)smB + wid * 1024;
  char* lB1 = (char*)smB + 4096;
  int lr = lane & 15, lg = lane >> 4;
  const short* pA = smA + (wid * 16 + lr) * 32 + lg * 8;
  const short* pB = smB + lr * 32 + lg * 8;
  f32x4 acc[5];
  const f32x4 fz = {0.f, 0.f, 0.f, 0.f};
  for (int i2 = 0; i2 < 5; ++i2) acc[i2] = fz;
  for (int ks = 0; ks < 88; ++ks) {
    const short* sA = (ks < 44) ? (sA_att + ks * 32) : (sA_baf + (ks - 44) * 32);
    gld16(sA, lA);
    gld16(sB0 + ks * 32, lB0);
    if (t < 64) gld16(sB1 + ks * 32, lB1);
    __syncthreads();
    bf16x8 a = *(const bf16x8*)pA;
#pragma unroll
    for (int ni = 0; ni < 5; ++ni) {
      bf16x8 b = *(const bf16x8*)(pB + ni * 512);
      acc[ni] = __builtin_amdgcn_mfma_f32_16x16x32_bf16(a, b, acc[ni], 0, 0, 0);
    }
    __syncthreads();
  }
#pragma unroll
  for (int ni = 0; ni < 5; ++ni) {
#pragma unroll
    for (int rg = 0; rg < 4; ++rg) {
      int n = ni * 16 + lr;
      int i = wid * 16 + lg * 4 + rg;
      int rgl = r0 + i;
      int p = rgl % PTOT;
      float v = acc[ni][rg] + bias80[n];
      if (n < 2) {
        out[(size_t)rgl * 77 + n] = v;
      } else if (n == 2) {
        out[(size_t)rgl * 77 + 2] =
            (anch[(size_t)p * 77 + 2] + 1.f / (1.f + __expf(-v))) * 0.5f;
        out[(size_t)rgl * 77 + 3] = anch[(size_t)p * 77 + 3];
      } else if (n < 76) {
        out[(size_t)rgl * 77 + n + 1] = v + anch[(size_t)p * 77 + n + 1];
      }
    }
  }
}

extern "C" void kernel_launch(void* const* d_in, const int* in_sizes, int n_in,
                              void* d_out, int out_size, void* d_ws, size_t ws_size,
                              hipStream_t stream) {
  const float* x      = (const float*)d_in[0];
  const float* conv_w = (const float*)d_in[1];
  const float* conv_b = (const float*)d_in[2];
  const float* att_w  = (const float*)d_in[3];
  const float* att_b  = (const float*)d_in[4];
  const float* cls_w  = (const float*)d_in[5];
  const float* cls_b  = (const float*)d_in[6];
  const float* so_w   = (const float*)d_in[7];
  const float* so_b   = (const float*)d_in[8];
  const float* reg_w  = (const float*)d_in[9];
  const float* reg_b  = (const float*)d_in[10];
  const float* anchors= (const float*)d_in[11];
  const int*   cut_xs = (const int*)d_in[12];
  const unsigned char* invalid = (const unsigned char*)d_in[13];

  float* out_rp = (float*)d_out;
  float* Mmat = out_rp + (size_t)ROWS * 77;
  float* feat = Mmat + (size_t)ROWS * PTOT;

  // workspace layout; base 231,858,688 B (proven), +124,010,496 for Msc (gated)
  char* wsp = (char*)d_ws;
  short* baf            = (short*)wsp;                          // 62,717,952
  unsigned char* bafT8  = (unsigned char*)(wsp + 62717952ULL);  // 34,603,008
  unsigned char* Mbf8   = (unsigned char*)(wsp + 97320960ULL);  // 63,438,848
  short* attw           = (short*)(wsp + 160759808ULL);         //  7,929,856
  short* wbf            = (short*)(wsp + 168689664ULL);         //    450,560
  float* bias80         = (float*)(wsp + 169140224ULL);         //        512
  short* attf           = (short*)(wsp + 169140736ULL);         // 62,717,952
  short* Msc            = (short*)(wsp + 231858688ULL);         // 124,010,496
  const size_t WS_FAST  = 231858688ULL + 124010496ULL;          // 355,869,184

  bool fast = (ws_size >= WS_FAST);

  k_conv<<<224, 256, 0, stream>>>(x, conv_w, conv_b, feat);
  k_prep<<<2048, 256, 0, stream>>>(att_w, cls_w, so_w, reg_w, cls_b, so_b, reg_b,
                                   attw, wbf, bias80, Mmat, Mbf8, bafT8,
                                   fast ? Msc : (short*)nullptr);
  k_gather<<<dim3(44, 24, 8), 256, 0, stream>>>(feat, cut_xs, invalid, baf, bafT8);
  if (fast) {
    k_scores<1><<<3828, 256, 0, stream>>>(baf, attw, att_b, (float*)nullptr, Msc);
    k_softmax<1><<<ROWS, 256, 0, stream>>>(Mmat, Mbf8, Msc);
  } else {
    k_scores<0><<<3828, 256, 0, stream>>>(baf, attw, att_b, Mmat, (short*)nullptr);
    k_softmax<0><<<ROWS, 256, 0, stream>>>(Mmat, Mbf8, (const short*)nullptr);
  }
  k_attfeat8<<<1936, 256, 0, stream>>>(Mbf8, bafT8, attf);
  k_head<<<348, 256, 0, stream>>>(attf, baf, wbf, bias80, anchors, out_rp);
}

// Round 12
// 637.161 us; speedup vs baseline: 1.0757x; 1.0757x over previous
//
#include <hip/hip_runtime.h>
#include <stdint.h>

#define PTOT 2784
#define PM1  2783
#define DDIM 1408
#define NB   8
#define ROWS 22272        // NB*PTOT
#define KHEAD 2816        // 2*DDIM
#define MROW 2816         // Mbf8 rows per batch, row stride 2816 B
#define BTROWS 1536       // bafT8 rows per batch, row stride 2816 B

typedef __attribute__((ext_vector_type(8))) short bf16x8;
typedef __attribute__((ext_vector_type(4))) float f32x4;
typedef long i64f8;       // 8 x fp8 fragment

__device__ __forceinline__ short f2bf_rne(float x) {
    uint32_t u = __float_as_uint(x);
    u += 0x7fffu + ((u >> 16) & 1u);
    return (short)(u >> 16);
}
__device__ __forceinline__ float bf2f(short s) {
    return __uint_as_float((uint32_t)(unsigned short)s << 16);
}

// f32 -> OCP e4m3fn, RNE, saturate at 448, flush |x|<2^-6 to 0
__device__ __forceinline__ unsigned char f2e4m3(float x) {
    uint32_t u = __float_as_uint(x);
    uint32_t sgn = (u >> 24) & 0x80u;
    uint32_t ax = u & 0x7fffffffu;
    ax += 0x7ffffu + ((ax >> 20) & 1u);          // RNE at 3 mantissa bits
    if (ax >= 0x43E80000u) return (unsigned char)(sgn | 0x7Eu);  // sat 448
    if (ax < 0x3C800000u) return (unsigned char)sgn;             // flush
    uint32_t e = (ax >> 23) - 120u;
    uint32_t m = (ax >> 20) & 7u;
    return (unsigned char)(sgn | (e << 3) | m);
}

// async global->LDS, 16B per lane. lds dest = wave-uniform base + lane*16.
__device__ __forceinline__ void gld16(const void* g, void* l) {
    __builtin_amdgcn_global_load_lds(
        (const __attribute__((address_space(1))) void*)(uintptr_t)g,
        (__attribute__((address_space(3))) void*)(uint32_t)(uintptr_t)l,
        16, 0, 0);
}

#define VMW(N) asm volatile("s_waitcnt vmcnt(" #N ")" ::: "memory")

// ---------------- kernel 1: 1x1 conv -> feat (f32, written to d_out) ----------
__global__ __launch_bounds__(256) void k_conv(
    const float* __restrict__ x, const float* __restrict__ w,
    const float* __restrict__ cb, float* __restrict__ feat) {
  __shared__ float xs[256 * 32];
  int b = blockIdx.x / 28;
  int t0 = (blockIdx.x % 28) * 32;
  int t = threadIdx.x;
  for (int i = t; i < 256 * 32; i += 256) {
    int c = i >> 5, pos = i & 31;
    int hw = t0 + pos;
    xs[i] = (hw < 880) ? x[((size_t)b * 256 + c) * 880 + hw] : 0.f;
  }
  __syncthreads();
  int o = t & 63, g = t >> 6;
  float acc[8];
#pragma unroll
  for (int pp = 0; pp < 8; ++pp) acc[pp] = cb[o];
  const float* wr = w + o * 256;
  for (int c = 0; c < 256; ++c) {
    float wv = wr[c];
#pragma unroll
    for (int pp = 0; pp < 8; ++pp) acc[pp] += wv * xs[c * 32 + g + pp * 4];
  }
#pragma unroll
  for (int pp = 0; pp < 8; ++pp) {
    int hw = t0 + g + pp * 4;
    if (hw < 880) feat[((size_t)b * 64 + o) * 880 + hw] = acc[pp];
  }
}

// ------- kernel 2: prep (bf16 weights, bias, diag seeds, fp8 pad zeroing) -----
__global__ __launch_bounds__(256) void k_prep(
    const float* __restrict__ att_w, const float* __restrict__ cls_w,
    const float* __restrict__ so_w, const float* __restrict__ reg_w,
    const float* __restrict__ cls_b, const float* __restrict__ so_b,
    const float* __restrict__ reg_b,
    short* __restrict__ attw, short* __restrict__ wbf,
    float* __restrict__ bias80, float* __restrict__ M,
    unsigned char* __restrict__ Mbf8, unsigned char* __restrict__ bafT8,
    short* __restrict__ Msc) {
  const int64_t n_attw = (int64_t)2816 * DDIM;
  const int64_t n_w = 80 * (int64_t)KHEAD;
  const int64_t n_pa = (int64_t)NB * MROW * 32;    // Mbf8 pad cols [2784,2816)
  const int64_t n_pb = (int64_t)NB * BTROWS * 32;  // bafT8 pad cols
  const int64_t total = n_attw + n_w + 80 + ROWS + n_pa + n_pb;
  for (int64_t i = (int64_t)blockIdx.x * 256 + threadIdx.x; i < total;
       i += (int64_t)gridDim.x * 256) {
    if (i < n_attw) {
      int j = (int)(i / DDIM), k = (int)(i - (int64_t)j * DDIM);
      float v = (j < PM1) ? att_w[(size_t)j * DDIM + k] : 0.f;
      attw[i] = f2bf_rne(v);
    } else if (i < n_attw + n_w) {
      int64_t ii = i - n_attw;
      int n = (int)(ii / KHEAD), k = (int)(ii - (int64_t)n * KHEAD);
      float v = 0.f;
      if (n < 2) v = cls_w[n * KHEAD + k];
      else if (n == 2) v = so_w[k];
      else if (n < 76) v = reg_w[(size_t)(n - 3) * KHEAD + k];
      wbf[ii] = f2bf_rne(v);
    } else if (i < n_attw + n_w + 80) {
      int n = (int)(i - n_attw - n_w);
      float v = 0.f;
      if (n < 2) v = cls_b[n];
      else if (n == 2) v = so_b[0];
      else if (n < 76) v = reg_b[n - 3];
      bias80[n] = v;
    } else if (i < n_attw + n_w + 80 + ROWS) {
      int r = (int)(i - n_attw - n_w - 80);
      int p = r % PTOT;
      M[(size_t)r * PTOT + p] = -1e30f;            // fallback path diag
      if (Msc) Msc[(size_t)r * PTOT + p] = f2bf_rne(-1e30f);  // fast path diag
    } else if (i < n_attw + n_w + 80 + ROWS + n_pa) {
      int64_t ii = i - n_attw - n_w - 80 - ROWS;
      int64_t row = ii >> 5; int c = (int)(ii & 31);
      Mbf8[row * 2816 + 2784 + c] = 0;
    } else {
      int64_t ii = i - n_attw - n_w - 80 - ROWS - n_pa;
      int64_t row = ii >> 5; int c = (int)(ii & 31);
      bafT8[row * 2816 + 2784 + c] = 0;
    }
  }
}

// ---------------- kernel 3: gather rois -> baf bf16 + bafT8 fp8 ---------------
__global__ __launch_bounds__(256) void k_gather(
    const float* __restrict__ feat, const int* __restrict__ cutx,
    const unsigned char* __restrict__ inval,
    short* __restrict__ baf, unsigned char* __restrict__ bafT8) {
  int p0 = blockIdx.x * 64, d0 = blockIdx.y * 64, b = blockIdx.z;
  __shared__ short tile[64][72];
  int t = threadIdx.x;
  for (int i = t; i < 64 * 64; i += 256) {
    int pl = i >> 6, dl = i & 63;
    int p = p0 + pl, d = d0 + dl;
    float v = 0.f;
    if (p < PTOT && d < DDIM) {
      int c = d / 22, h = d - c * 22;
      if (!inval[p * 22 + h]) {
        int xc = cutx[p * 22 + h];
        v = feat[(((size_t)b * 64 + c) * 22 + h) * 40 + xc];
      }
    }
    tile[pl][dl] = f2bf_rne(v);
  }
  __syncthreads();
  if (d0 < DDIM) {
    for (int u = t; u < 512; u += 256) {   // baf rows: coalesced along d
      int pl = u >> 3, dg = u & 7;
      int p = p0 + pl;
      if (p < PTOT) {
        bf16x8 v;
#pragma unroll
        for (int e = 0; e < 8; ++e) v[e] = tile[pl][dg * 8 + e];
        *(bf16x8*)&baf[((size_t)b * PTOT + p) * DDIM + d0 + dg * 8] = v;
      }
    }
  }
  for (int u = t; u < 512; u += 256) {     // bafT8 rows: fp8, stride 2816
    int dl = u >> 3, pg = u & 7;
    int pbase = p0 + pg * 8;
    if (pbase + 7 < PTOT) {
      unsigned long long pk = 0;
#pragma unroll
      for (int e = 0; e < 8; ++e) {
        float fv = bf2f(tile[pg * 8 + e][dl]);
        pk |= (unsigned long long)f2e4m3(fv) << (8 * e);
      }
      *(unsigned long long*)&bafT8[((size_t)b * BTROWS + d0 + dl) * 2816 + pbase] = pk;
    }
  }
}

// ===== scores: 128x256 8-wave bf16, 3-slot static pipeline, 72KB LDS ==========
// 24KB/tile (A 8KB + B 16KB), 3 gld16/thread/tile, VMW(6/3/0), raw s_barrier.
// 2 blocks/CU (LDS 144KB), 16 waves/CU. Staged bytes 0.75x of the 128x128 form.
// LDS involution f(x)=x^(((x>>7)&3)<<4) on region-relative offsets; staging
// pre-swizzles the per-lane GLOBAL source, gld16 dest stays linear (rule 21).
#define SC_TILE(OFF_, S_, SN_, STAGE_, VM_)                                    \
  {                                                                            \
    const char* cb_ = sm + (S_) * 24576;                                       \
    if (STAGE_) {                                                              \
      char* nb_ = sm + (SN_) * 24576;                                          \
      gld16(gA0 + (OFF_), nb_ + ddA);                                          \
      gld16(gB0 + (OFF_), nb_ + 8192 + ddA);                                   \
      gld16(gB1 + (OFF_), nb_ + 16384 + ddA);                                  \
    }                                                                          \
    if ((VM_) == 6) VMW(6); else if ((VM_) == 3) VMW(3); else VMW(0);          \
    __builtin_amdgcn_s_barrier();                                              \
    bf16x8 av[4], bv[4];                                                       \
    _Pragma("unroll") for (int i = 0; i < 4; ++i)                              \
      av[i] = *(const bf16x8*)(cb_ + offA[i]);                                 \
    _Pragma("unroll") for (int i = 0; i < 4; ++i)                              \
      bv[i] = *(const bf16x8*)(cb_ + 8192 + offB[i]);                          \
    _Pragma("unroll") for (int mi = 0; mi < 4; ++mi)                           \
      _Pragma("unroll") for (int ni = 0; ni < 4; ++ni)                         \
        acc[mi][ni] = __builtin_amdgcn_mfma_f32_16x16x32_bf16(                 \
            av[mi], bv[ni], acc[mi][ni], 0, 0, 0);                             \
    __builtin_amdgcn_s_barrier();                                              \
  }

template<int OUTMODE>
__global__ __launch_bounds__(512, 4) void k_scores(
    const short* __restrict__ baf, const short* __restrict__ attw,
    const float* __restrict__ att_b, float* __restrict__ Mout,
    short* __restrict__ Msc) {
  __shared__ char sm[73728];                 // 3 x 24KB
  int wg = blockIdx.x;                       // 1914 = 174 it x 11 nt; q=239 r=2
  int xcd = wg & 7, lin = wg >> 3;
  int wgid = (xcd < 2) ? xcd * 240 + lin : 480 + (xcd - 2) * 239 + lin;
  int it = wgid / 11, nt = wgid - it * 11;   // nt fastest: A-panel L2 reuse
  int m0 = it * 128, n0 = nt * 256;

  int t = threadIdx.x, w = t >> 6, l = t & 63;
  int lr = l & 15, lg = l >> 4;
  int wr = w >> 2, wc = w & 3;               // 2 x 4 wave grid

  // staging sources: A (8KB, rows m0..m0+127), B (16KB, rows n0..n0+255)
  const char* gA0; const char* gB0; const char* gB1;
  int ddA = t * 16;
  {
    int oA = t * 16;                         // A-region-relative
    int rA = oA >> 6, cA = (oA & 63) ^ (((oA >> 7) & 3) << 4);
    gA0 = (const char*)(baf + (size_t)(m0 + rA) * DDIM) + cA;
    int oB0 = t * 16;                        // B-region-relative 0..8191
    int rB0 = oB0 >> 6, cB0 = (oB0 & 63) ^ (((oB0 >> 7) & 3) << 4);
    gB0 = (const char*)(attw + (size_t)(n0 + rB0) * DDIM) + cB0;
    int oB1 = 8192 + t * 16;                 // B-region-relative 8192..16383
    int rB1 = oB1 >> 6, cB1 = (oB1 & 63) ^ (((oB1 >> 7) & 3) << 4);
    gB1 = (const char*)(attw + (size_t)(n0 + rB1) * DDIM) + cB1;
  }
  int offA[4], offB[4];
#pragma unroll
  for (int i = 0; i < 4; ++i) {
    int xa = (wr * 64 + i * 16 + lr) * 64 + lg * 16;
    offA[i] = xa ^ (((xa >> 7) & 3) << 4);
    int xb = (wc * 64 + i * 16 + lr) * 64 + lg * 16;
    offB[i] = xb ^ (((xb >> 7) & 3) << 4);
  }

  f32x4 acc[4][4];
  const f32x4 fz = {0.f, 0.f, 0.f, 0.f};
#pragma unroll
  for (int mi = 0; mi < 4; ++mi)
#pragma unroll
    for (int ni = 0; ni < 4; ++ni) acc[mi][ni] = fz;

  // prologue: stage tiles 0 -> slot0, 1 -> slot1 (6 loads outstanding)
  gld16(gA0, sm + ddA);
  gld16(gB0, sm + 8192 + ddA);
  gld16(gB1, sm + 16384 + ddA);
  gld16(gA0 + 64, sm + 24576 + ddA);
  gld16(gB0 + 64, sm + 24576 + 8192 + ddA);
  gld16(gB1 + 64, sm + 24576 + 16384 + ddA);

  for (int q = 0; q < 14; ++q) {             // tiles 3q..3q+2, slots 0,1,2
    SC_TILE(128, 0, 2, 1, 6);
    SC_TILE(192, 1, 0, 1, 6);
    SC_TILE(256, 2, 1, 1, 6);
    gA0 += 192; gB0 += 192; gB1 += 192;
  }
  SC_TILE(0, 0, 0, 0, 3);                    // tile 42, slot 0
  SC_TILE(0, 1, 0, 0, 0);                    // tile 43, slot 1

#pragma unroll
  for (int mi = 0; mi < 4; ++mi) {
#pragma unroll
    for (int rg = 0; rg < 4; ++rg) {
      int gmi = m0 + wr * 64 + mi * 16 + lg * 4 + rg;
      int i = gmi % PTOT;
#pragma unroll
      for (int ni = 0; ni < 4; ++ni) {
        int j = n0 + wc * 64 + ni * 16 + lr;
        if (j < PM1) {
          int q2 = j + (j >= i);
          float v = acc[mi][ni][rg] + att_b[j];
          if (OUTMODE == 0) Mout[(size_t)gmi * PTOT + q2] = v;
          else              Msc[(size_t)gmi * PTOT + q2] = f2bf_rne(v);
        }
      }
    }
  }
}

// ===== attfeat: 128x256 8-wave FP8, 3-slot static pipeline, 72KB LDS ==========
#define AF_TILE(OFF_, S_, SN_, STAGE_, VM_)                                    \
  {                                                                            \
    const char* cb_ = sm + (S_) * 24576;                                       \
    if (STAGE_) {                                                              \
      char* nb_ = sm + (SN_) * 24576;                                          \
      gld16(gA0 + (OFF_), nb_ + ddA);                                          \
      gld16(gB0 + (OFF_), nb_ + 8192 + ddA);                                   \
      gld16(gB1 + (OFF_), nb_ + 16384 + ddA);                                  \
    }                                                                          \
    if ((VM_) == 6) VMW(6); else if ((VM_) == 3) VMW(3); else VMW(0);          \
    __builtin_amdgcn_s_barrier();                                              \
    _Pragma("unroll") for (int ks = 0; ks < 2; ++ks) {                         \
      i64f8 av[4], bv[4];                                                      \
      _Pragma("unroll") for (int i = 0; i < 4; ++i)                            \
        av[i] = *(const i64f8*)(cb_ + offA[i * 2 + ks]);                       \
      _Pragma("unroll") for (int i = 0; i < 4; ++i)                            \
        bv[i] = *(const i64f8*)(cb_ + 8192 + offB[i * 2 + ks]);                \
      _Pragma("unroll") for (int mi = 0; mi < 4; ++mi)                         \
        _Pragma("unroll") for (int ni = 0; ni < 4; ++ni)                       \
          acc[mi][ni] = __builtin_amdgcn_mfma_f32_16x16x32_fp8_fp8(            \
              av[mi], bv[ni], acc[mi][ni], 0, 0, 0);                           \
    }                                                                          \
    __builtin_amdgcn_s_barrier();                                              \
  }

__global__ __launch_bounds__(512, 4) void k_attfeat8(
    const unsigned char* __restrict__ Mbf8,
    const unsigned char* __restrict__ bafT8,
    short* __restrict__ attf) {
  __shared__ char sm[73728];
  int wg = blockIdx.x;                       // 1056 = 8 * 132
  int wgid = (wg & 7) * 132 + (wg >> 3);     // XCD-chunked, bijective
  int bb = wgid / 132;
  int rem = wgid - bb * 132;
  int it = rem / 6, dt = rem - it * 6;       // dt fastest: A-panel reuse
  int m0 = it * 128, n0 = dt * 256;
  const unsigned char* Ab = Mbf8 + ((size_t)bb * MROW + m0) * 2816;
  const unsigned char* Bb = bafT8 + ((size_t)bb * BTROWS + n0) * 2816;

  int t = threadIdx.x, w = t >> 6, l = t & 63;
  int lr = l & 15, lg = l >> 4;
  int wr = w >> 2, wc = w & 3;

  // staging: A (8KB: 128 rows x 64B fp8 BK=64), B (16KB: 256 rows x 64B)
  const char* gA0; const char* gB0; const char* gB1;
  int ddA = t * 16;
  {
    int oA = t * 16;
    int rA = oA >> 6, cA = (oA & 63) ^ (((oA >> 7) & 3) << 4);
    gA0 = (const char*)Ab + (size_t)rA * 2816 + cA;
    int oB0 = t * 16;
    int rB0 = oB0 >> 6, cB0 = (oB0 & 63) ^ (((oB0 >> 7) & 3) << 4);
    gB0 = (const char*)Bb + (size_t)rB0 * 2816 + cB0;
    int oB1 = 8192 + t * 16;
    int rB1 = oB1 >> 6, cB1 = (oB1 & 63) ^ (((oB1 >> 7) & 3) << 4);
    gB1 = (const char*)Bb + (size_t)rB1 * 2816 + cB1;
  }
  int offA[8], offB[8];
#pragma unroll
  for (int i = 0; i < 4; ++i) {
#pragma unroll
    for (int ks = 0; ks < 2; ++ks) {
      int xa = (wr * 64 + i * 16 + lr) * 64 + ks * 32 + lg * 8;
      offA[i * 2 + ks] = xa ^ (((xa >> 7) & 3) << 4);
      int xb = (wc * 64 + i * 16 + lr) * 64 + ks * 32 + lg * 8;
      offB[i * 2 + ks] = xb ^ (((xb >> 7) & 3) << 4);
    }
  }

  f32x4 acc[4][4];
  const f32x4 fz = {0.f, 0.f, 0.f, 0.f};
#pragma unroll
  for (int mi = 0; mi < 4; ++mi)
#pragma unroll
    for (int ni = 0; ni < 4; ++ni) acc[mi][ni] = fz;

  // prologue: stage tiles 0,1
  gld16(gA0, sm + ddA);
  gld16(gB0, sm + 8192 + ddA);
  gld16(gB1, sm + 16384 + ddA);
  gld16(gA0 + 64, sm + 24576 + ddA);
  gld16(gB0 + 64, sm + 24576 + 8192 + ddA);
  gld16(gB1 + 64, sm + 24576 + 16384 + ddA);

  for (int q = 0; q < 14; ++q) {             // 44 K-tiles of 64 (K=2816)
    AF_TILE(128, 0, 2, 1, 6);
    AF_TILE(192, 1, 0, 1, 6);
    AF_TILE(256, 2, 1, 1, 6);
    gA0 += 192; gB0 += 192; gB1 += 192;
  }
  AF_TILE(0, 0, 0, 0, 3);                    // tile 42
  AF_TILE(0, 1, 0, 0, 0);                    // tile 43

  const float US = 1.0f / 1024.0f;
#pragma unroll
  for (int mi = 0; mi < 4; ++mi) {
#pragma unroll
    for (int rg = 0; rg < 4; ++rg) {
      int i = m0 + wr * 64 + mi * 16 + lg * 4 + rg;
      if (i < PTOT) {
        short* arow = attf + ((size_t)(bb * PTOT + i)) * DDIM;
#pragma unroll
        for (int ni = 0; ni < 4; ++ni) {
          int d = n0 + wc * 64 + ni * 16 + lr;
          if (d < DDIM) arow[d] = f2bf_rne(acc[mi][ni][rg] * US);
        }
      }
    }
  }
}

// -------- kernel 5: row softmax -> f32 M (required output) + fp8 Mbf8 ---------
template<int INMODE>
__global__ __launch_bounds__(256) void k_softmax(float* __restrict__ M,
                                                 unsigned char* __restrict__ Mbf8,
                                                 const short* __restrict__ Msc) {
  __shared__ float red[8];
  int r = blockIdx.x;
  int b = r / PTOT, p = r - b * PTOT;
  float* pr = M + (size_t)r * PTOT;
  const short* ms = INMODE ? (Msc + (size_t)r * PTOT) : (const short*)nullptr;
  unsigned char* mb = Mbf8 + ((size_t)b * MROW + p) * 2816;
  int t = threadIdx.x;
  bool has2 = (t < 348 - 256);
  float v0[8], v1[8];
  float mx = -3.0e38f;
  if (INMODE == 0) {
    f32x4 a0 = *(const f32x4*)(pr + t * 8);
    f32x4 a1 = *(const f32x4*)(pr + t * 8 + 4);
#pragma unroll
    for (int e = 0; e < 4; ++e) { v0[e] = a0[e]; v0[4 + e] = a1[e]; }
  } else {
    bf16x8 a = *(const bf16x8*)(ms + t * 8);
#pragma unroll
    for (int e = 0; e < 8; ++e) v0[e] = bf2f(a[e]);
  }
#pragma unroll
  for (int e = 0; e < 8; ++e) mx = fmaxf(mx, v0[e]);
  if (has2) {
    if (INMODE == 0) {
      f32x4 b0 = *(const f32x4*)(pr + (256 + t) * 8);
      f32x4 b1 = *(const f32x4*)(pr + (256 + t) * 8 + 4);
#pragma unroll
      for (int e = 0; e < 4; ++e) { v1[e] = b0[e]; v1[4 + e] = b1[e]; }
    } else {
      bf16x8 bb = *(const bf16x8*)(ms + (256 + t) * 8);
#pragma unroll
      for (int e = 0; e < 8; ++e) v1[e] = bf2f(bb[e]);
    }
#pragma unroll
    for (int e = 0; e < 8; ++e) mx = fmaxf(mx, v1[e]);
  }
#pragma unroll
  for (int off = 32; off; off >>= 1) mx = fmaxf(mx, __shfl_xor(mx, off));
  if ((t & 63) == 0) red[t >> 6] = mx;
  __syncthreads();
  mx = fmaxf(fmaxf(red[0], red[1]), fmaxf(red[2], red[3]));
  float s = 0.f;
#pragma unroll
  for (int e = 0; e < 8; ++e) { v0[e] = __expf(v0[e] - mx); s += v0[e]; }
  if (has2) {
#pragma unroll
    for (int e = 0; e < 8; ++e) { v1[e] = __expf(v1[e] - mx); s += v1[e]; }
  }
#pragma unroll
  for (int off = 32; off; off >>= 1) s += __shfl_xor(s, off);
  if ((t & 63) == 0) red[4 + (t >> 6)] = s;
  __syncthreads();
  s = (red[4] + red[5]) + (red[6] + red[7]);
  float inv = 1.f / s;
  float invs = inv * 1024.f;
  {
    f32x4 o0, o1; unsigned long long pk = 0;
#pragma unroll
    for (int e = 0; e < 8; ++e) {
      float wv = v0[e] * inv;
      if (e < 4) o0[e] = wv; else o1[e - 4] = wv;
      pk |= (unsigned long long)f2e4m3(v0[e] * invs) << (8 * e);
    }
    *(f32x4*)(pr + t * 8) = o0;
    *(f32x4*)(pr + t * 8 + 4) = o1;
    *(unsigned long long*)(mb + t * 8) = pk;
  }
  if (has2) {
    f32x4 o0, o1; unsigned long long pk = 0;
#pragma unroll
    for (int e = 0; e < 8; ++e) {
      float wv = v1[e] * inv;
      if (e < 4) o0[e] = wv; else o1[e - 4] = wv;
      pk |= (unsigned long long)f2e4m3(v1[e] * invs) << (8 * e);
    }
    *(f32x4*)(pr + (256 + t) * 8) = o0;
    *(f32x4*)(pr + (256 + t) * 8 + 4) = o1;
    *(unsigned long long*)(mb + (256 + t) * 8) = pk;
  }
}

// ---------------- kernel 7: heads GEMM + proposal assembly --------------------
__global__ __launch_bounds__(256) void k_head(
    const short* __restrict__ attf, const short* __restrict__ baf,
    const short* __restrict__ wbf, const float* __restrict__ bias80,
    const float* __restrict__ anch, float* __restrict__ out) {
  __shared__ short smA[64 * 32];
  __shared__ short smB[80 * 32];
  int r0 = blockIdx.x * 64;
  int t = threadIdx.x, wid = t >> 6, lane = t & 63;
  int rowa = t >> 2, kg = t & 3;
  const short* sA_att = attf + (size_t)(r0 + rowa) * DDIM + kg * 8;
  const short* sA_baf = baf + (size_t)(r0 + rowa) * DDIM + kg * 8;
  const short* sB0 = wbf + (size_t)rowa * KHEAD + kg * 8;
  const short* sB1 = wbf + (size_t)(64 + (t >> 2)) * KHEAD + (t & 3) * 8;
  char* lA = (char*)smA + wid * 1024;
  char* lB0 = (char*)smB + wid * 1024;
  char* lB1 = (char*)smB + 4096;
  int lr = lane & 15, lg = lane >> 4;
  const short* pA = smA + (wid * 16 + lr) * 32 + lg * 8;
  const short* pB = smB + lr * 32 + lg * 8;
  f32x4 acc[5];
  const f32x4 fz = {0.f, 0.f, 0.f, 0.f};
  for (int i2 = 0; i2 < 5; ++i2) acc[i2] = fz;
  for (int ks = 0; ks < 88; ++ks) {
    const short* sA = (ks < 44) ? (sA_att + ks * 32) : (sA_baf + (ks - 44) * 32);
    gld16(sA, lA);
    gld16(sB0 + ks * 32, lB0);
    if (t < 64) gld16(sB1 + ks * 32, lB1);
    __syncthreads();
    bf16x8 a = *(const bf16x8*)pA;
#pragma unroll
    for (int ni = 0; ni < 5; ++ni) {
      bf16x8 b = *(const bf16x8*)(pB + ni * 512);
      acc[ni] = __builtin_amdgcn_mfma_f32_16x16x32_bf16(a, b, acc[ni], 0, 0, 0);
    }
    __syncthreads();
  }
#pragma unroll
  for (int ni = 0; ni < 5; ++ni) {
#pragma unroll
    for (int rg = 0; rg < 4; ++rg) {
      int n = ni * 16 + lr;
      int i = wid * 16 + lg * 4 + rg;
      int rgl = r0 + i;
      int p = rgl % PTOT;
      float v = acc[ni][rg] + bias80[n];
      if (n < 2) {
        out[(size_t)rgl * 77 + n] = v;
      } else if (n == 2) {
        out[(size_t)rgl * 77 + 2] =
            (anch[(size_t)p * 77 + 2] + 1.f / (1.f + __expf(-v))) * 0.5f;
        out[(size_t)rgl * 77 + 3] = anch[(size_t)p * 77 + 3];
      } else if (n < 76) {
        out[(size_t)rgl * 77 + n + 1] = v + anch[(size_t)p * 77 + n + 1];
      }
    }
  }
}

extern "C" void kernel_launch(void* const* d_in, const int* in_sizes, int n_in,
                              void* d_out, int out_size, void* d_ws, size_t ws_size,
                              hipStream_t stream) {
  const float* x      = (const float*)d_in[0];
  const float* conv_w = (const float*)d_in[1];
  const float* conv_b = (const float*)d_in[2];
  const float* att_w  = (const float*)d_in[3];
  const float* att_b  = (const float*)d_in[4];
  const float* cls_w  = (const float*)d_in[5];
  const float* cls_b  = (const float*)d_in[6];
  const float* so_w   = (const float*)d_in[7];
  const float* so_b   = (const float*)d_in[8];
  const float* reg_w  = (const float*)d_in[9];
  const float* reg_b  = (const float*)d_in[10];
  const float* anchors= (const float*)d_in[11];
  const int*   cut_xs = (const int*)d_in[12];
  const unsigned char* invalid = (const unsigned char*)d_in[13];

  float* out_rp = (float*)d_out;
  float* Mmat = out_rp + (size_t)ROWS * 77;
  float* feat = Mmat + (size_t)ROWS * PTOT;

  // workspace layout; base 231,858,688 B (proven), +124,010,496 for Msc (gated)
  char* wsp = (char*)d_ws;
  short* baf            = (short*)wsp;                          // 62,717,952
  unsigned char* bafT8  = (unsigned char*)(wsp + 62717952ULL);  // 34,603,008
  unsigned char* Mbf8   = (unsigned char*)(wsp + 97320960ULL);  // 63,438,848
  short* attw           = (short*)(wsp + 160759808ULL);         //  7,929,856
  short* wbf            = (short*)(wsp + 168689664ULL);         //    450,560
  float* bias80         = (float*)(wsp + 169140224ULL);         //        512
  short* attf           = (short*)(wsp + 169140736ULL);         // 62,717,952
  short* Msc            = (short*)(wsp + 231858688ULL);         // 124,010,496
  const size_t WS_FAST  = 231858688ULL + 124010496ULL;          // 355,869,184

  bool fast = (ws_size >= WS_FAST);

  k_conv<<<224, 256, 0, stream>>>(x, conv_w, conv_b, feat);
  k_prep<<<2048, 256, 0, stream>>>(att_w, cls_w, so_w, reg_w, cls_b, so_b, reg_b,
                                   attw, wbf, bias80, Mmat, Mbf8, bafT8,
                                   fast ? Msc : (short*)nullptr);
  k_gather<<<dim3(44, 24, 8), 256, 0, stream>>>(feat, cut_xs, invalid, baf, bafT8);
  if (fast) {
    k_scores<1><<<1914, 512, 0, stream>>>(baf, attw, att_b, (float*)nullptr, Msc);
    k_softmax<1><<<ROWS, 256, 0, stream>>>(Mmat, Mbf8, Msc);
  } else {
    k_scores<0><<<1914, 512, 0, stream>>>(baf, attw, att_b, Mmat, (short*)nullptr);
    k_softmax<0><<<ROWS, 256, 0, stream>>>(Mmat, Mbf8, (const short*)nullptr);
  }
  k_attfeat8<<<1056, 512, 0, stream>>>(Mbf8, bafT8, attf);
  k_head<<<348, 256, 0, stream>>>(attf, baf, wbf, bias80, anchors, out_rp);
}

// Round 13
// 617.572 us; speedup vs baseline: 1.1098x; 1.0317x over previous
//
#include <hip/hip_runtime.h>
#include <stdint.h>

#define PTOT 2784
#define PM1  2783
#define DDIM 1408
#define NB   8
#define ROWS 22272        // NB*PTOT
#define KHEAD 2816        // 2*DDIM
#define MROW 2816         // Mbf8 rows per batch, row stride 2816 B
#define BTROWS 1536       // bafT8 rows per batch, row stride 2816 B

typedef __attribute__((ext_vector_type(8))) short bf16x8;
typedef __attribute__((ext_vector_type(4))) float f32x4;
typedef long i64f8;       // 8 x fp8 fragment
typedef __attribute__((ext_vector_type(2))) long i64x2;  // 16B = {ks0,ks1} frags

__device__ __forceinline__ short f2bf_rne(float x) {
    uint32_t u = __float_as_uint(x);
    u += 0x7fffu + ((u >> 16) & 1u);
    return (short)(u >> 16);
}
__device__ __forceinline__ float bf2f(short s) {
    return __uint_as_float((uint32_t)(unsigned short)s << 16);
}

// f32 -> OCP e4m3fn, RNE, saturate at 448, flush |x|<2^-6 to 0
__device__ __forceinline__ unsigned char f2e4m3(float x) {
    uint32_t u = __float_as_uint(x);
    uint32_t sgn = (u >> 24) & 0x80u;
    uint32_t ax = u & 0x7fffffffu;
    ax += 0x7ffffu + ((ax >> 20) & 1u);          // RNE at 3 mantissa bits
    if (ax >= 0x43E80000u) return (unsigned char)(sgn | 0x7Eu);  // sat 448
    if (ax < 0x3C800000u) return (unsigned char)sgn;             // flush
    uint32_t e = (ax >> 23) - 120u;
    uint32_t m = (ax >> 20) & 7u;
    return (unsigned char)(sgn | (e << 3) | m);
}

// ks-interleave permutation of fp8 k-order within each 64B row-block:
// orig byte c -> (c&~63) + g*16 + ks*8 + (c&7), g=(c>>3)&3, ks=(c>>5)&1.
// Makes a lane's {ks0,ks1} 8B fragments adjacent -> ds_read_b128 in attfeat.
__device__ __forceinline__ size_t kperm(size_t c) {
    return (c & ~(size_t)63) + (((c >> 3) & 3) << 4) + (((c >> 5) & 1) << 3) + (c & 7);
}

// async global->LDS, 16B per lane. lds dest = wave-uniform base + lane*16.
__device__ __forceinline__ void gld16(const void* g, void* l) {
    __builtin_amdgcn_global_load_lds(
        (const __attribute__((address_space(1))) void*)(uintptr_t)g,
        (__attribute__((address_space(3))) void*)(uint32_t)(uintptr_t)l,
        16, 0, 0);
}

#define VMW(N) asm volatile("s_waitcnt vmcnt(" #N ")" ::: "memory")

// ---------------- kernel 1: 1x1 conv -> feat (f32, written to d_out) ----------
__global__ __launch_bounds__(256) void k_conv(
    const float* __restrict__ x, const float* __restrict__ w,
    const float* __restrict__ cb, float* __restrict__ feat) {
  __shared__ float xs[256 * 32];
  int b = blockIdx.x / 28;
  int t0 = (blockIdx.x % 28) * 32;
  int t = threadIdx.x;
  for (int i = t; i < 256 * 32; i += 256) {
    int c = i >> 5, pos = i & 31;
    int hw = t0 + pos;
    xs[i] = (hw < 880) ? x[((size_t)b * 256 + c) * 880 + hw] : 0.f;
  }
  __syncthreads();
  int o = t & 63, g = t >> 6;
  float acc[8];
#pragma unroll
  for (int pp = 0; pp < 8; ++pp) acc[pp] = cb[o];
  const float* wr = w + o * 256;
  for (int c = 0; c < 256; ++c) {
    float wv = wr[c];
#pragma unroll
    for (int pp = 0; pp < 8; ++pp) acc[pp] += wv * xs[c * 32 + g + pp * 4];
  }
#pragma unroll
  for (int pp = 0; pp < 8; ++pp) {
    int hw = t0 + g + pp * 4;
    if (hw < 880) feat[((size_t)b * 64 + o) * 880 + hw] = acc[pp];
  }
}

// ------- kernel 2: prep (bf16 weights, bias, diag seeds, fp8 pad zeroing) -----
__global__ __launch_bounds__(256) void k_prep(
    const float* __restrict__ att_w, const float* __restrict__ cls_w,
    const float* __restrict__ so_w, const float* __restrict__ reg_w,
    const float* __restrict__ cls_b, const float* __restrict__ so_b,
    const float* __restrict__ reg_b,
    short* __restrict__ attw, short* __restrict__ wbf,
    float* __restrict__ bias80, float* __restrict__ M,
    unsigned char* __restrict__ Mbf8, unsigned char* __restrict__ bafT8,
    short* __restrict__ Msc) {
  const int64_t n_attw = (int64_t)2816 * DDIM;
  const int64_t n_w = 80 * (int64_t)KHEAD;
  const int64_t n_pa = (int64_t)NB * MROW * 32;    // Mbf8 pad cols [2784,2816)
  const int64_t n_pb = (int64_t)NB * BTROWS * 32;  // bafT8 pad cols
  const int64_t total = n_attw + n_w + 80 + ROWS + n_pa + n_pb;
  for (int64_t i = (int64_t)blockIdx.x * 256 + threadIdx.x; i < total;
       i += (int64_t)gridDim.x * 256) {
    if (i < n_attw) {
      int j = (int)(i / DDIM), k = (int)(i - (int64_t)j * DDIM);
      float v = (j < PM1) ? att_w[(size_t)j * DDIM + k] : 0.f;
      attw[i] = f2bf_rne(v);
    } else if (i < n_attw + n_w) {
      int64_t ii = i - n_attw;
      int n = (int)(ii / KHEAD), k = (int)(ii - (int64_t)n * KHEAD);
      float v = 0.f;
      if (n < 2) v = cls_w[n * KHEAD + k];
      else if (n == 2) v = so_w[k];
      else if (n < 76) v = reg_w[(size_t)(n - 3) * KHEAD + k];
      wbf[ii] = f2bf_rne(v);
    } else if (i < n_attw + n_w + 80) {
      int n = (int)(i - n_attw - n_w);
      float v = 0.f;
      if (n < 2) v = cls_b[n];
      else if (n == 2) v = so_b[0];
      else if (n < 76) v = reg_b[n - 3];
      bias80[n] = v;
    } else if (i < n_attw + n_w + 80 + ROWS) {
      int r = (int)(i - n_attw - n_w - 80);
      int p = r % PTOT;
      M[(size_t)r * PTOT + p] = -1e30f;            // fallback path diag
      if (Msc) Msc[(size_t)r * PTOT + p] = f2bf_rne(-1e30f);  // fast path diag
    } else if (i < n_attw + n_w + 80 + ROWS + n_pa) {
      int64_t ii = i - n_attw - n_w - 80 - ROWS;
      int64_t row = ii >> 5; int c = (int)(ii & 31);
      Mbf8[row * 2816 + kperm(2784 + c)] = 0;
    } else {
      int64_t ii = i - n_attw - n_w - 80 - ROWS - n_pa;
      int64_t row = ii >> 5; int c = (int)(ii & 31);
      bafT8[row * 2816 + kperm(2784 + c)] = 0;
    }
  }
}

// ---------------- kernel 3: gather rois -> baf bf16 + bafT8 fp8 (k-perm) ------
__global__ __launch_bounds__(256) void k_gather(
    const float* __restrict__ feat, const int* __restrict__ cutx,
    const unsigned char* __restrict__ inval,
    short* __restrict__ baf, unsigned char* __restrict__ bafT8) {
  int p0 = blockIdx.x * 64, d0 = blockIdx.y * 64, b = blockIdx.z;
  __shared__ short tile[64][72];
  int t = threadIdx.x;
  for (int i = t; i < 64 * 64; i += 256) {
    int pl = i >> 6, dl = i & 63;
    int p = p0 + pl, d = d0 + dl;
    float v = 0.f;
    if (p < PTOT && d < DDIM) {
      int c = d / 22, h = d - c * 22;
      if (!inval[p * 22 + h]) {
        int xc = cutx[p * 22 + h];
        v = feat[(((size_t)b * 64 + c) * 22 + h) * 40 + xc];
      }
    }
    tile[pl][dl] = f2bf_rne(v);
  }
  __syncthreads();
  if (d0 < DDIM) {
    for (int u = t; u < 512; u += 256) {   // baf rows: coalesced along d
      int pl = u >> 3, dg = u & 7;
      int p = p0 + pl;
      if (p < PTOT) {
        bf16x8 v;
#pragma unroll
        for (int e = 0; e < 8; ++e) v[e] = tile[pl][dg * 8 + e];
        *(bf16x8*)&baf[((size_t)b * PTOT + p) * DDIM + d0 + dg * 8] = v;
      }
    }
  }
  for (int u = t; u < 512; u += 256) {     // bafT8 rows: fp8, k-permuted
    int dl = u >> 3, pg = u & 7;
    int pbase = p0 + pg * 8;
    if (pbase + 7 < PTOT) {
      unsigned long long pk = 0;
#pragma unroll
      for (int e = 0; e < 8; ++e) {
        float fv = bf2f(tile[pg * 8 + e][dl]);
        pk |= (unsigned long long)f2e4m3(fv) << (8 * e);
      }
      *(unsigned long long*)&bafT8[((size_t)b * BTROWS + d0 + dl) * 2816 +
                                   kperm(pbase)] = pk;
    }
  }
}

// ===== scores: 128x256 8-wave bf16, 3-slot static pipeline, 72KB LDS ==========
// (unchanged from R12 -- control)
#define SC_TILE(OFF_, S_, SN_, STAGE_, VM_)                                    \
  {                                                                            \
    const char* cb_ = sm + (S_) * 24576;                                       \
    if (STAGE_) {                                                              \
      char* nb_ = sm + (SN_) * 24576;                                          \
      gld16(gA0 + (OFF_), nb_ + ddA);                                          \
      gld16(gB0 + (OFF_), nb_ + 8192 + ddA);                                   \
      gld16(gB1 + (OFF_), nb_ + 16384 + ddA);                                  \
    }                                                                          \
    if ((VM_) == 6) VMW(6); else if ((VM_) == 3) VMW(3); else VMW(0);          \
    __builtin_amdgcn_s_barrier();                                              \
    bf16x8 av[4], bv[4];                                                       \
    _Pragma("unroll") for (int i = 0; i < 4; ++i)                              \
      av[i] = *(const bf16x8*)(cb_ + offA[i]);                                 \
    _Pragma("unroll") for (int i = 0; i < 4; ++i)                              \
      bv[i] = *(const bf16x8*)(cb_ + 8192 + offB[i]);                          \
    _Pragma("unroll") for (int mi = 0; mi < 4; ++mi)                           \
      _Pragma("unroll") for (int ni = 0; ni < 4; ++ni)                         \
        acc[mi][ni] = __builtin_amdgcn_mfma_f32_16x16x32_bf16(                 \
            av[mi], bv[ni], acc[mi][ni], 0, 0, 0);                             \
    __builtin_amdgcn_s_barrier();                                              \
  }

template<int OUTMODE>
__global__ __launch_bounds__(512, 4) void k_scores(
    const short* __restrict__ baf, const short* __restrict__ attw,
    const float* __restrict__ att_b, float* __restrict__ Mout,
    short* __restrict__ Msc) {
  __shared__ char sm[73728];                 // 3 x 24KB
  int wg = blockIdx.x;                       // 1914 = 174 it x 11 nt; q=239 r=2
  int xcd = wg & 7, lin = wg >> 3;
  int wgid = (xcd < 2) ? xcd * 240 + lin : 480 + (xcd - 2) * 239 + lin;
  int it = wgid / 11, nt = wgid - it * 11;   // nt fastest: A-panel L2 reuse
  int m0 = it * 128, n0 = nt * 256;

  int t = threadIdx.x, w = t >> 6, l = t & 63;
  int lr = l & 15, lg = l >> 4;
  int wr = w >> 2, wc = w & 3;               // 2 x 4 wave grid

  const char* gA0; const char* gB0; const char* gB1;
  int ddA = t * 16;
  {
    int oA = t * 16;
    int rA = oA >> 6, cA = (oA & 63) ^ (((oA >> 7) & 3) << 4);
    gA0 = (const char*)(baf + (size_t)(m0 + rA) * DDIM) + cA;
    int oB0 = t * 16;
    int rB0 = oB0 >> 6, cB0 = (oB0 & 63) ^ (((oB0 >> 7) & 3) << 4);
    gB0 = (const char*)(attw + (size_t)(n0 + rB0) * DDIM) + cB0;
    int oB1 = 8192 + t * 16;
    int rB1 = oB1 >> 6, cB1 = (oB1 & 63) ^ (((oB1 >> 7) & 3) << 4);
    gB1 = (const char*)(attw + (size_t)(n0 + rB1) * DDIM) + cB1;
  }
  int offA[4], offB[4];
#pragma unroll
  for (int i = 0; i < 4; ++i) {
    int xa = (wr * 64 + i * 16 + lr) * 64 + lg * 16;
    offA[i] = xa ^ (((xa >> 7) & 3) << 4);
    int xb = (wc * 64 + i * 16 + lr) * 64 + lg * 16;
    offB[i] = xb ^ (((xb >> 7) & 3) << 4);
  }

  f32x4 acc[4][4];
  const f32x4 fz = {0.f, 0.f, 0.f, 0.f};
#pragma unroll
  for (int mi = 0; mi < 4; ++mi)
#pragma unroll
    for (int ni = 0; ni < 4; ++ni) acc[mi][ni] = fz;

  gld16(gA0, sm + ddA);
  gld16(gB0, sm + 8192 + ddA);
  gld16(gB1, sm + 16384 + ddA);
  gld16(gA0 + 64, sm + 24576 + ddA);
  gld16(gB0 + 64, sm + 24576 + 8192 + ddA);
  gld16(gB1 + 64, sm + 24576 + 16384 + ddA);

  for (int q = 0; q < 14; ++q) {
    SC_TILE(128, 0, 2, 1, 6);
    SC_TILE(192, 1, 0, 1, 6);
    SC_TILE(256, 2, 1, 1, 6);
    gA0 += 192; gB0 += 192; gB1 += 192;
  }
  SC_TILE(0, 0, 0, 0, 3);
  SC_TILE(0, 1, 0, 0, 0);

#pragma unroll
  for (int mi = 0; mi < 4; ++mi) {
#pragma unroll
    for (int rg = 0; rg < 4; ++rg) {
      int gmi = m0 + wr * 64 + mi * 16 + lg * 4 + rg;
      int i = gmi % PTOT;
#pragma unroll
      for (int ni = 0; ni < 4; ++ni) {
        int j = n0 + wc * 64 + ni * 16 + lr;
        if (j < PM1) {
          int q2 = j + (j >= i);
          float v = acc[mi][ni][rg] + att_b[j];
          if (OUTMODE == 0) Mout[(size_t)gmi * PTOT + q2] = v;
          else              Msc[(size_t)gmi * PTOT + q2] = f2bf_rne(v);
        }
      }
    }
  }
}

// ===== attfeat: 128x256 8-wave FP8, 3-slot pipeline, b128 LDS reads ===========
// fp8 k-order is ks-interleaved in global (kperm) so each lane's {ks0,ks1}
// fragments are one b128: 8 ds_read_b128/wave/tile instead of 16 ds_read_b64.
#define AF_TILE(OFF_, S_, SN_, STAGE_, VM_)                                    \
  {                                                                            \
    const char* cb_ = sm + (S_) * 24576;                                       \
    if (STAGE_) {                                                              \
      char* nb_ = sm + (SN_) * 24576;                                          \
      gld16(gA0 + (OFF_), nb_ + ddA);                                          \
      gld16(gB0 + (OFF_), nb_ + 8192 + ddA);                                   \
      gld16(gB1 + (OFF_), nb_ + 16384 + ddA);                                  \
    }                                                                          \
    if ((VM_) == 6) VMW(6); else if ((VM_) == 3) VMW(3); else VMW(0);          \
    __builtin_amdgcn_s_barrier();                                              \
    i64x2 aw[4], bw[4];                                                        \
    _Pragma("unroll") for (int i = 0; i < 4; ++i)                              \
      aw[i] = *(const i64x2*)(cb_ + offA[i]);                                  \
    _Pragma("unroll") for (int i = 0; i < 4; ++i)                              \
      bw[i] = *(const i64x2*)(cb_ + 8192 + offB[i]);                           \
    _Pragma("unroll") for (int ks = 0; ks < 2; ++ks)                           \
      _Pragma("unroll") for (int mi = 0; mi < 4; ++mi)                         \
        _Pragma("unroll") for (int ni = 0; ni < 4; ++ni)                       \
          acc[mi][ni] = __builtin_amdgcn_mfma_f32_16x16x32_fp8_fp8(            \
              aw[mi][ks], bw[ni][ks], acc[mi][ni], 0, 0, 0);                   \
    __builtin_amdgcn_s_barrier();                                              \
  }

__global__ __launch_bounds__(512, 4) void k_attfeat8(
    const unsigned char* __restrict__ Mbf8,
    const unsigned char* __restrict__ bafT8,
    short* __restrict__ attf) {
  __shared__ char sm[73728];
  int wg = blockIdx.x;                       // 1056 = 8 * 132
  int wgid = (wg & 7) * 132 + (wg >> 3);     // XCD-chunked, bijective
  int bb = wgid / 132;
  int rem = wgid - bb * 132;
  int it = rem / 6, dt = rem - it * 6;       // dt fastest: A-panel reuse
  int m0 = it * 128, n0 = dt * 256;
  const unsigned char* Ab = Mbf8 + ((size_t)bb * MROW + m0) * 2816;
  const unsigned char* Bb = bafT8 + ((size_t)bb * BTROWS + n0) * 2816;

  int t = threadIdx.x, w = t >> 6, l = t & 63;
  int lr = l & 15, lg = l >> 4;
  int wr = w >> 2, wc = w & 3;

  const char* gA0; const char* gB0; const char* gB1;
  int ddA = t * 16;
  {
    int oA = t * 16;
    int rA = oA >> 6, cA = (oA & 63) ^ (((oA >> 7) & 3) << 4);
    gA0 = (const char*)Ab + (size_t)rA * 2816 + cA;
    int oB0 = t * 16;
    int rB0 = oB0 >> 6, cB0 = (oB0 & 63) ^ (((oB0 >> 7) & 3) << 4);
    gB0 = (const char*)Bb + (size_t)rB0 * 2816 + cB0;
    int oB1 = 8192 + t * 16;
    int rB1 = oB1 >> 6, cB1 = (oB1 & 63) ^ (((oB1 >> 7) & 3) << 4);
    gB1 = (const char*)Bb + (size_t)rB1 * 2816 + cB1;
  }
  // b128 read offsets: one 16B read = {ks0 frag, ks1 frag} (k-perm layout)
  int offA[4], offB[4];
#pragma unroll
  for (int i = 0; i < 4; ++i) {
    int xa = (wr * 64 + i * 16 + lr) * 64 + lg * 16;
    offA[i] = xa ^ (((xa >> 7) & 3) << 4);
    int xb = (wc * 64 + i * 16 + lr) * 64 + lg * 16;
    offB[i] = xb ^ (((xb >> 7) & 3) << 4);
  }

  f32x4 acc[4][4];
  const f32x4 fz = {0.f, 0.f, 0.f, 0.f};
#pragma unroll
  for (int mi = 0; mi < 4; ++mi)
#pragma unroll
    for (int ni = 0; ni < 4; ++ni) acc[mi][ni] = fz;

  gld16(gA0, sm + ddA);
  gld16(gB0, sm + 8192 + ddA);
  gld16(gB1, sm + 16384 + ddA);
  gld16(gA0 + 64, sm + 24576 + ddA);
  gld16(gB0 + 64, sm + 24576 + 8192 + ddA);
  gld16(gB1 + 64, sm + 24576 + 16384 + ddA);

  for (int q = 0; q < 14; ++q) {             // 44 K-tiles of 64 (K=2816)
    AF_TILE(128, 0, 2, 1, 6);
    AF_TILE(192, 1, 0, 1, 6);
    AF_TILE(256, 2, 1, 1, 6);
    gA0 += 192; gB0 += 192; gB1 += 192;
  }
  AF_TILE(0, 0, 0, 0, 3);
  AF_TILE(0, 1, 0, 0, 0);

  const float US = 1.0f / 1024.0f;
#pragma unroll
  for (int mi = 0; mi < 4; ++mi) {
#pragma unroll
    for (int rg = 0; rg < 4; ++rg) {
      int i = m0 + wr * 64 + mi * 16 + lg * 4 + rg;
      if (i < PTOT) {
        short* arow = attf + ((size_t)(bb * PTOT + i)) * DDIM;
#pragma unroll
        for (int ni = 0; ni < 4; ++ni) {
          int d = n0 + wc * 64 + ni * 16 + lr;
          if (d < DDIM) arow[d] = f2bf_rne(acc[mi][ni][rg] * US);
        }
      }
    }
  }
}

// -------- kernel 5: row softmax -> f32 M + fp8 Mbf8 (k-permuted) --------------
template<int INMODE>
__global__ __launch_bounds__(256) void k_softmax(float* __restrict__ M,
                                                 unsigned char* __restrict__ Mbf8,
                                                 const short* __restrict__ Msc) {
  __shared__ float red[8];
  int r = blockIdx.x;
  int b = r / PTOT, p = r - b * PTOT;
  float* pr = M + (size_t)r * PTOT;
  const short* ms = INMODE ? (Msc + (size_t)r * PTOT) : (const short*)nullptr;
  unsigned char* mb = Mbf8 + ((size_t)b * MROW + p) * 2816;
  int t = threadIdx.x;
  bool has2 = (t < 348 - 256);
  float v0[8], v1[8];
  float mx = -3.0e38f;
  if (INMODE == 0) {
    f32x4 a0 = *(const f32x4*)(pr + t * 8);
    f32x4 a1 = *(const f32x4*)(pr + t * 8 + 4);
#pragma unroll
    for (int e = 0; e < 4; ++e) { v0[e] = a0[e]; v0[4 + e] = a1[e]; }
  } else {
    bf16x8 a = *(const bf16x8*)(ms + t * 8);
#pragma unroll
    for (int e = 0; e < 8; ++e) v0[e] = bf2f(a[e]);
  }
#pragma unroll
  for (int e = 0; e < 8; ++e) mx = fmaxf(mx, v0[e]);
  if (has2) {
    if (INMODE == 0) {
      f32x4 b0 = *(const f32x4*)(pr + (256 + t) * 8);
      f32x4 b1 = *(const f32x4*)(pr + (256 + t) * 8 + 4);
#pragma unroll
      for (int e = 0; e < 4; ++e) { v1[e] = b0[e]; v1[4 + e] = b1[e]; }
    } else {
      bf16x8 bb = *(const bf16x8*)(ms + (256 + t) * 8);
#pragma unroll
      for (int e = 0; e < 8; ++e) v1[e] = bf2f(bb[e]);
    }
#pragma unroll
    for (int e = 0; e < 8; ++e) mx = fmaxf(mx, v1[e]);
  }
#pragma unroll
  for (int off = 32; off; off >>= 1) mx = fmaxf(mx, __shfl_xor(mx, off));
  if ((t & 63) == 0) red[t >> 6] = mx;
  __syncthreads();
  mx = fmaxf(fmaxf(red[0], red[1]), fmaxf(red[2], red[3]));
  float s = 0.f;
#pragma unroll
  for (int e = 0; e < 8; ++e) { v0[e] = __expf(v0[e] - mx); s += v0[e]; }
  if (has2) {
#pragma unroll
    for (int e = 0; e < 8; ++e) { v1[e] = __expf(v1[e] - mx); s += v1[e]; }
  }
#pragma unroll
  for (int off = 32; off; off >>= 1) s += __shfl_xor(s, off);
  if ((t & 63) == 0) red[4 + (t >> 6)] = s;
  __syncthreads();
  s = (red[4] + red[5]) + (red[6] + red[7]);
  float inv = 1.f / s;
  float invs = inv * 1024.f;
  {
    f32x4 o0, o1; unsigned long long pk = 0;
#pragma unroll
    for (int e = 0; e < 8; ++e) {
      float wv = v0[e] * inv;
      if (e < 4) o0[e] = wv; else o1[e - 4] = wv;
      pk |= (unsigned long long)f2e4m3(v0[e] * invs) << (8 * e);
    }
    *(f32x4*)(pr + t * 8) = o0;
    *(f32x4*)(pr + t * 8 + 4) = o1;
    *(unsigned long long*)(mb + kperm((size_t)t * 8)) = pk;
  }
  if (has2) {
    f32x4 o0, o1; unsigned long long pk = 0;
#pragma unroll
    for (int e = 0; e < 8; ++e) {
      float wv = v1[e] * inv;
      if (e < 4) o0[e] = wv; else o1[e - 4] = wv;
      pk |= (unsigned long long)f2e4m3(v1[e] * invs) << (8 * e);
    }
    *(f32x4*)(pr + (256 + t) * 8) = o0;
    *(f32x4*)(pr + (256 + t) * 8 + 4) = o1;
    *(unsigned long long*)(mb + kperm((size_t)(256 + t) * 8)) = pk;
  }
}

// ---- kernel 7: heads GEMM + proposal assembly (3-slot counted-vmcnt) ---------
// 348 blocks x 64 rows, 256 thr. Per tile: A 4KB (1 load/thr), B 80x64B=5KB
// (1 load/thr + extra for t<64). Slots 9216B x 3. Full unroll -> static slots.
__global__ __launch_bounds__(256) void k_head(
    const short* __restrict__ attf, const short* __restrict__ baf,
    const short* __restrict__ wbf, const float* __restrict__ bias80,
    const float* __restrict__ anch, float* __restrict__ out) {
  __shared__ char sm[27648];                 // 3 x 9216
  int r0 = blockIdx.x * 64;
  int t = threadIdx.x, w = t >> 6, lane = t & 63;
  int lr = lane & 15, lg = lane >> 4;
  int ddA = t * 16;
  const char* gA_att = (const char*)(attf + (size_t)(r0 + (t >> 2)) * DDIM) + (t & 3) * 16;
  const char* gA_baf = (const char*)(baf + (size_t)(r0 + (t >> 2)) * DDIM) + (t & 3) * 16;
  const char* gB1 = (const char*)(wbf + (size_t)(t >> 2) * KHEAD) + (t & 3) * 16;
  const char* gB2 = (const char*)(wbf + (size_t)(64 + (t >> 2)) * KHEAD) + (t & 3) * 16;
  int pAo = (w * 16 + lr) * 64 + lg * 16;    // A: row (w*16+lr), 16B
  int pBo = 4096 + lr * 64 + lg * 16;        // B: row lr (+ni*16), 16B
  f32x4 acc[5];
  const f32x4 fz = {0.f, 0.f, 0.f, 0.f};
#pragma unroll
  for (int i2 = 0; i2 < 5; ++i2) acc[i2] = fz;

  // prologue: stage tiles 0,1 into slots 0,1
#pragma unroll
  for (int s = 0; s < 2; ++s) {
    char* nb = sm + s * 9216;
    gld16(gA_att + s * 64, nb + ddA);
    gld16(gB1 + s * 64, nb + 4096 + ddA);
    if (t < 64) gld16(gB2 + s * 64, nb + 8192 + ddA);
  }

#pragma unroll
  for (int kt = 0; kt < 88; ++kt) {
    const char* cb_ = sm + (kt % 3) * 9216;
    int s = kt + 2;
    if (s < 88) {
      char* nb_ = sm + (s % 3) * 9216;
      const char* asrc = (s < 44) ? (gA_att + s * 64) : (gA_baf + (s - 44) * 64);
      gld16(asrc, nb_ + ddA);
      gld16(gB1 + s * 64, nb_ + 4096 + ddA);
      if (t < 64) gld16(gB2 + s * 64, nb_ + 8192 + ddA);
    }
    if (w == 0) { if (kt < 86) VMW(6); else if (kt == 86) VMW(3); else VMW(0); }
    else        { if (kt < 86) VMW(4); else if (kt == 86) VMW(2); else VMW(0); }
    __builtin_amdgcn_s_barrier();
    bf16x8 a = *(const bf16x8*)(cb_ + pAo);
#pragma unroll
    for (int ni = 0; ni < 5; ++ni) {
      bf16x8 bvv = *(const bf16x8*)(cb_ + pBo + ni * 1024);
      acc[ni] = __builtin_amdgcn_mfma_f32_16x16x32_bf16(a, bvv, acc[ni], 0, 0, 0);
    }
    __builtin_amdgcn_s_barrier();
  }

#pragma unroll
  for (int ni = 0; ni < 5; ++ni) {
#pragma unroll
    for (int rg = 0; rg < 4; ++rg) {
      int n = ni * 16 + lr;
      int i = w * 16 + lg * 4 + rg;
      int rgl = r0 + i;
      int p = rgl % PTOT;
      float v = acc[ni][rg] + bias80[n];
      if (n < 2) {
        out[(size_t)rgl * 77 + n] = v;
      } else if (n == 2) {
        out[(size_t)rgl * 77 + 2] =
            (anch[(size_t)p * 77 + 2] + 1.f / (1.f + __expf(-v))) * 0.5f;
        out[(size_t)rgl * 77 + 3] = anch[(size_t)p * 77 + 3];
      } else if (n < 76) {
        out[(size_t)rgl * 77 + n + 1] = v + anch[(size_t)p * 77 + n + 1];
      }
    }
  }
}

extern "C" void kernel_launch(void* const* d_in, const int* in_sizes, int n_in,
                              void* d_out, int out_size, void* d_ws, size_t ws_size,
                              hipStream_t stream) {
  const float* x      = (const float*)d_in[0];
  const float* conv_w = (const float*)d_in[1];
  const float* conv_b = (const float*)d_in[2];
  const float* att_w  = (const float*)d_in[3];
  const float* att_b  = (const float*)d_in[4];
  const float* cls_w  = (const float*)d_in[5];
  const float* cls_b  = (const float*)d_in[6];
  const float* so_w   = (const float*)d_in[7];
  const float* so_b   = (const float*)d_in[8];
  const float* reg_w  = (const float*)d_in[9];
  const float* reg_b  = (const float*)d_in[10];
  const float* anchors= (const float*)d_in[11];
  const int*   cut_xs = (const int*)d_in[12];
  const unsigned char* invalid = (const unsigned char*)d_in[13];

  float* out_rp = (float*)d_out;
  float* Mmat = out_rp + (size_t)ROWS * 77;
  float* feat = Mmat + (size_t)ROWS * PTOT;

  // workspace layout; base 231,858,688 B (proven), +124,010,496 for Msc (gated)
  char* wsp = (char*)d_ws;
  short* baf            = (short*)wsp;                          // 62,717,952
  unsigned char* bafT8  = (unsigned char*)(wsp + 62717952ULL);  // 34,603,008
  unsigned char* Mbf8   = (unsigned char*)(wsp + 97320960ULL);  // 63,438,848
  short* attw           = (short*)(wsp + 160759808ULL);         //  7,929,856
  short* wbf            = (short*)(wsp + 168689664ULL);         //    450,560
  float* bias80         = (float*)(wsp + 169140224ULL);         //        512
  short* attf           = (short*)(wsp + 169140736ULL);         // 62,717,952
  short* Msc            = (short*)(wsp + 231858688ULL);         // 124,010,496
  const size_t WS_FAST  = 231858688ULL + 124010496ULL;          // 355,869,184

  bool fast = (ws_size >= WS_FAST);

  k_conv<<<224, 256, 0, stream>>>(x, conv_w, conv_b, feat);
  k_prep<<<2048, 256, 0, stream>>>(att_w, cls_w, so_w, reg_w, cls_b, so_b, reg_b,
                                   attw, wbf, bias80, Mmat, Mbf8, bafT8,
                                   fast ? Msc : (short*)nullptr);
  k_gather<<<dim3(44, 24, 8), 256, 0, stream>>>(feat, cut_xs, invalid, baf, bafT8);
  if (fast) {
    k_scores<1><<<1914, 512, 0, stream>>>(baf, attw, att_b, (float*)nullptr, Msc);
    k_softmax<1><<<ROWS, 256, 0, stream>>>(Mmat, Mbf8, Msc);
  } else {
    k_scores<0><<<1914, 512, 0, stream>>>(baf, attw, att_b, Mmat, (short*)nullptr);
    k_softmax<0><<<ROWS, 256, 0, stream>>>(Mmat, Mbf8, (const short*)nullptr);
  }
  k_attfeat8<<<1056, 512, 0, stream>>>(Mbf8, bafT8, attf);
  k_head<<<348, 256, 0, stream>>>(attf, baf, wbf, bias80, anchors, out_rp);
}

// Round 14
// 606.684 us; speedup vs baseline: 1.1297x; 1.0179x over previous
//
#include <hip/hip_runtime.h>
#include <stdint.h>

#define PTOT 2784
#define PM1  2783
#define DDIM 1408
#define NB   8
#define ROWS 22272        // NB*PTOT
#define KHEAD 2816        // 2*DDIM
#define MROW 2816         // Mbf8 rows per batch, row stride 2816 B
#define BTROWS 1536       // bafT8 rows per batch, row stride 2816 B

typedef __attribute__((ext_vector_type(8))) short bf16x8;
typedef __attribute__((ext_vector_type(4))) float f32x4;
typedef long i64f8;       // 8 x fp8 fragment
typedef __attribute__((ext_vector_type(2))) long i64x2;  // 16B = {ks0,ks1} frags

__device__ __forceinline__ short f2bf_rne(float x) {
    uint32_t u = __float_as_uint(x);
    u += 0x7fffu + ((u >> 16) & 1u);
    return (short)(u >> 16);
}
__device__ __forceinline__ float bf2f(short s) {
    return __uint_as_float((uint32_t)(unsigned short)s << 16);
}

// f32 -> OCP e4m3fn, RNE, saturate at 448, flush |x|<2^-6 to 0
__device__ __forceinline__ unsigned char f2e4m3(float x) {
    uint32_t u = __float_as_uint(x);
    uint32_t sgn = (u >> 24) & 0x80u;
    uint32_t ax = u & 0x7fffffffu;
    ax += 0x7ffffu + ((ax >> 20) & 1u);          // RNE at 3 mantissa bits
    if (ax >= 0x43E80000u) return (unsigned char)(sgn | 0x7Eu);  // sat 448
    if (ax < 0x3C800000u) return (unsigned char)sgn;             // flush
    uint32_t e = (ax >> 23) - 120u;
    uint32_t m = (ax >> 20) & 7u;
    return (unsigned char)(sgn | (e << 3) | m);
}

// ks-interleave permutation of fp8 k-order within each 64B row-block:
// orig byte c -> (c&~63) + g*16 + ks*8 + (c&7), g=(c>>3)&3, ks=(c>>5)&1.
__device__ __forceinline__ uint32_t kperm(uint32_t c) {
    return (c & ~63u) + (((c >> 3) & 3) << 4) + (((c >> 5) & 1) << 3) + (c & 7);
}

// async global->LDS, 16B per lane. lds dest = wave-uniform base + lane*16.
__device__ __forceinline__ void gld16(const void* g, void* l) {
    __builtin_amdgcn_global_load_lds(
        (const __attribute__((address_space(1))) void*)(uintptr_t)g,
        (__attribute__((address_space(3))) void*)(uint32_t)(uintptr_t)l,
        16, 0, 0);
}

#define VMW(N) asm volatile("s_waitcnt vmcnt(" #N ")" ::: "memory")

// ---------------- kernel 1: 1x1 conv -> feat (f32, written to d_out) ----------
__global__ __launch_bounds__(256) void k_conv(
    const float* __restrict__ x, const float* __restrict__ w,
    const float* __restrict__ cb, float* __restrict__ feat) {
  __shared__ float xs[256 * 32];
  int b = blockIdx.x / 28;
  int t0 = (blockIdx.x % 28) * 32;
  int t = threadIdx.x;
  for (int i = t; i < 256 * 32; i += 256) {
    int c = i >> 5, pos = i & 31;
    int hw = t0 + pos;
    xs[i] = (hw < 880) ? x[((size_t)b * 256 + c) * 880 + hw] : 0.f;
  }
  __syncthreads();
  int o = t & 63, g = t >> 6;
  float acc[8];
#pragma unroll
  for (int pp = 0; pp < 8; ++pp) acc[pp] = cb[o];
  const float* wr = w + o * 256;
  for (int c = 0; c < 256; ++c) {
    float wv = wr[c];
#pragma unroll
    for (int pp = 0; pp < 8; ++pp) acc[pp] += wv * xs[c * 32 + g + pp * 4];
  }
#pragma unroll
  for (int pp = 0; pp < 8; ++pp) {
    int hw = t0 + g + pp * 4;
    if (hw < 880) feat[((size_t)b * 64 + o) * 880 + hw] = acc[pp];
  }
}

// ------- kernel 2: prep (32-bit indexing -- no int64 div in hot loop) ---------
__global__ __launch_bounds__(256) void k_prep(
    const float* __restrict__ att_w, const float* __restrict__ cls_w,
    const float* __restrict__ so_w, const float* __restrict__ reg_w,
    const float* __restrict__ cls_b, const float* __restrict__ so_b,
    const float* __restrict__ reg_b,
    short* __restrict__ attw, short* __restrict__ wbf,
    float* __restrict__ bias80, float* __restrict__ M,
    unsigned char* __restrict__ Mbf8, unsigned char* __restrict__ bafT8,
    short* __restrict__ Msc) {
  const uint32_t n_attw = 2816u * DDIM;            // 3,964,928
  const uint32_t n_w = 80u * KHEAD;                // 225,280
  const uint32_t n_pa = (uint32_t)NB * MROW * 32;  // 720,896
  const uint32_t n_pb = (uint32_t)NB * BTROWS * 32;// 393,216
  const uint32_t total = n_attw + n_w + 80 + ROWS + n_pa + n_pb;
  for (uint32_t i = blockIdx.x * 256 + threadIdx.x; i < total;
       i += gridDim.x * 256) {
    if (i < n_attw) {
      uint32_t j = i / DDIM, k = i - j * DDIM;
      float v = (j < PM1) ? att_w[(size_t)j * DDIM + k] : 0.f;
      attw[i] = f2bf_rne(v);
    } else if (i < n_attw + n_w) {
      uint32_t ii = i - n_attw;
      uint32_t n = ii / KHEAD, k = ii - n * KHEAD;
      float v = 0.f;
      if (n < 2) v = cls_w[n * KHEAD + k];
      else if (n == 2) v = so_w[k];
      else if (n < 76) v = reg_w[(size_t)(n - 3) * KHEAD + k];
      wbf[ii] = f2bf_rne(v);
    } else if (i < n_attw + n_w + 80) {
      uint32_t n = i - n_attw - n_w;
      float v = 0.f;
      if (n < 2) v = cls_b[n];
      else if (n == 2) v = so_b[0];
      else if (n < 76) v = reg_b[n - 3];
      bias80[n] = v;
    } else if (i < n_attw + n_w + 80 + ROWS) {
      uint32_t r = i - n_attw - n_w - 80;
      uint32_t p = r % PTOT;
      M[(size_t)r * PTOT + p] = -1e30f;            // fallback path diag
      if (Msc) Msc[(size_t)r * PTOT + p] = f2bf_rne(-1e30f);  // fast path diag
    } else if (i < n_attw + n_w + 80 + ROWS + n_pa) {
      uint32_t ii = i - n_attw - n_w - 80 - ROWS;
      uint32_t row = ii >> 5; uint32_t c = ii & 31;
      Mbf8[(size_t)row * 2816 + kperm(2784 + c)] = 0;
    } else {
      uint32_t ii = i - n_attw - n_w - 80 - ROWS - n_pa;
      uint32_t row = ii >> 5; uint32_t c = ii & 31;
      bafT8[(size_t)row * 2816 + kperm(2784 + c)] = 0;
    }
  }
}

// ---------------- kernel 3: gather rois -> baf bf16 + bafT8 fp8 (k-perm) ------
__global__ __launch_bounds__(256) void k_gather(
    const float* __restrict__ feat, const int* __restrict__ cutx,
    const unsigned char* __restrict__ inval,
    short* __restrict__ baf, unsigned char* __restrict__ bafT8) {
  int p0 = blockIdx.x * 64, d0 = blockIdx.y * 64, b = blockIdx.z;
  __shared__ short tile[64][72];
  int t = threadIdx.x;
  for (int i = t; i < 64 * 64; i += 256) {
    int pl = i >> 6, dl = i & 63;
    int p = p0 + pl, d = d0 + dl;
    float v = 0.f;
    if (p < PTOT && d < DDIM) {
      int c = d / 22, h = d - c * 22;
      if (!inval[p * 22 + h]) {
        int xc = cutx[p * 22 + h];
        v = feat[(((size_t)b * 64 + c) * 22 + h) * 40 + xc];
      }
    }
    tile[pl][dl] = f2bf_rne(v);
  }
  __syncthreads();
  if (d0 < DDIM) {
    for (int u = t; u < 512; u += 256) {   // baf rows: coalesced along d
      int pl = u >> 3, dg = u & 7;
      int p = p0 + pl;
      if (p < PTOT) {
        bf16x8 v;
#pragma unroll
        for (int e = 0; e < 8; ++e) v[e] = tile[pl][dg * 8 + e];
        *(bf16x8*)&baf[((size_t)b * PTOT + p) * DDIM + d0 + dg * 8] = v;
      }
    }
  }
  for (int u = t; u < 512; u += 256) {     // bafT8 rows: fp8, k-permuted
    int dl = u >> 3, pg = u & 7;
    int pbase = p0 + pg * 8;
    if (pbase + 7 < PTOT) {
      unsigned long long pk = 0;
#pragma unroll
      for (int e = 0; e < 8; ++e) {
        float fv = bf2f(tile[pg * 8 + e][dl]);
        pk |= (unsigned long long)f2e4m3(fv) << (8 * e);
      }
      *(unsigned long long*)&bafT8[((size_t)b * BTROWS + d0 + dl) * 2816 +
                                   kperm(pbase)] = pk;
    }
  }
}

// ===== scores: 128x256 8-wave bf16, 3-slot static pipeline + setprio (T5) =====
#define SC_TILE(OFF_, S_, SN_, STAGE_, VM_)                                    \
  {                                                                            \
    const char* cb_ = sm + (S_) * 24576;                                       \
    if (STAGE_) {                                                              \
      char* nb_ = sm + (SN_) * 24576;                                          \
      gld16(gA0 + (OFF_), nb_ + ddA);                                          \
      gld16(gB0 + (OFF_), nb_ + 8192 + ddA);                                   \
      gld16(gB1 + (OFF_), nb_ + 16384 + ddA);                                  \
    }                                                                          \
    if ((VM_) == 6) VMW(6); else if ((VM_) == 3) VMW(3); else VMW(0);          \
    __builtin_amdgcn_s_barrier();                                              \
    bf16x8 av[4], bv[4];                                                       \
    _Pragma("unroll") for (int i = 0; i < 4; ++i)                              \
      av[i] = *(const bf16x8*)(cb_ + offA[i]);                                 \
    _Pragma("unroll") for (int i = 0; i < 4; ++i)                              \
      bv[i] = *(const bf16x8*)(cb_ + 8192 + offB[i]);                          \
    __builtin_amdgcn_s_setprio(1);                                             \
    _Pragma("unroll") for (int mi = 0; mi < 4; ++mi)                           \
      _Pragma("unroll") for (int ni = 0; ni < 4; ++ni)                         \
        acc[mi][ni] = __builtin_amdgcn_mfma_f32_16x16x32_bf16(                 \
            av[mi], bv[ni], acc[mi][ni], 0, 0, 0);                             \
    __builtin_amdgcn_s_setprio(0);                                             \
    __builtin_amdgcn_s_barrier();                                              \
  }

template<int OUTMODE>
__global__ __launch_bounds__(512, 4) void k_scores(
    const short* __restrict__ baf, const short* __restrict__ attw,
    const float* __restrict__ att_b, float* __restrict__ Mout,
    short* __restrict__ Msc) {
  __shared__ char sm[73728];                 // 3 x 24KB
  int wg = blockIdx.x;                       // 1914 = 174 it x 11 nt; q=239 r=2
  int xcd = wg & 7, lin = wg >> 3;
  int wgid = (xcd < 2) ? xcd * 240 + lin : 480 + (xcd - 2) * 239 + lin;
  int it = wgid / 11, nt = wgid - it * 11;   // nt fastest: A-panel L2 reuse
  int m0 = it * 128, n0 = nt * 256;

  int t = threadIdx.x, w = t >> 6, l = t & 63;
  int lr = l & 15, lg = l >> 4;
  int wr = w >> 2, wc = w & 3;               // 2 x 4 wave grid

  const char* gA0; const char* gB0; const char* gB1;
  int ddA = t * 16;
  {
    int oA = t * 16;
    int rA = oA >> 6, cA = (oA & 63) ^ (((oA >> 7) & 3) << 4);
    gA0 = (const char*)(baf + (size_t)(m0 + rA) * DDIM) + cA;
    int oB0 = t * 16;
    int rB0 = oB0 >> 6, cB0 = (oB0 & 63) ^ (((oB0 >> 7) & 3) << 4);
    gB0 = (const char*)(attw + (size_t)(n0 + rB0) * DDIM) + cB0;
    int oB1 = 8192 + t * 16;
    int rB1 = oB1 >> 6, cB1 = (oB1 & 63) ^ (((oB1 >> 7) & 3) << 4);
    gB1 = (const char*)(attw + (size_t)(n0 + rB1) * DDIM) + cB1;
  }
  int offA[4], offB[4];
#pragma unroll
  for (int i = 0; i < 4; ++i) {
    int xa = (wr * 64 + i * 16 + lr) * 64 + lg * 16;
    offA[i] = xa ^ (((xa >> 7) & 3) << 4);
    int xb = (wc * 64 + i * 16 + lr) * 64 + lg * 16;
    offB[i] = xb ^ (((xb >> 7) & 3) << 4);
  }

  f32x4 acc[4][4];
  const f32x4 fz = {0.f, 0.f, 0.f, 0.f};
#pragma unroll
  for (int mi = 0; mi < 4; ++mi)
#pragma unroll
    for (int ni = 0; ni < 4; ++ni) acc[mi][ni] = fz;

  gld16(gA0, sm + ddA);
  gld16(gB0, sm + 8192 + ddA);
  gld16(gB1, sm + 16384 + ddA);
  gld16(gA0 + 64, sm + 24576 + ddA);
  gld16(gB0 + 64, sm + 24576 + 8192 + ddA);
  gld16(gB1 + 64, sm + 24576 + 16384 + ddA);

  for (int q = 0; q < 14; ++q) {
    SC_TILE(128, 0, 2, 1, 6);
    SC_TILE(192, 1, 0, 1, 6);
    SC_TILE(256, 2, 1, 1, 6);
    gA0 += 192; gB0 += 192; gB1 += 192;
  }
  SC_TILE(0, 0, 0, 0, 3);
  SC_TILE(0, 1, 0, 0, 0);

#pragma unroll
  for (int mi = 0; mi < 4; ++mi) {
#pragma unroll
    for (int rg = 0; rg < 4; ++rg) {
      int gmi = m0 + wr * 64 + mi * 16 + lg * 4 + rg;
      int i = gmi % PTOT;
#pragma unroll
      for (int ni = 0; ni < 4; ++ni) {
        int j = n0 + wc * 64 + ni * 16 + lr;
        if (j < PM1) {
          int q2 = j + (j >= i);
          float v = acc[mi][ni][rg] + att_b[j];
          if (OUTMODE == 0) Mout[(size_t)gmi * PTOT + q2] = v;
          else              Msc[(size_t)gmi * PTOT + q2] = f2bf_rne(v);
        }
      }
    }
  }
}

// ===== attfeat: 128x256 8-wave FP8, 3-slot pipeline, b128 reads + setprio =====
#define AF_TILE(OFF_, S_, SN_, STAGE_, VM_)                                    \
  {                                                                            \
    const char* cb_ = sm + (S_) * 24576;                                       \
    if (STAGE_) {                                                              \
      char* nb_ = sm + (SN_) * 24576;                                          \
      gld16(gA0 + (OFF_), nb_ + ddA);                                          \
      gld16(gB0 + (OFF_), nb_ + 8192 + ddA);                                   \
      gld16(gB1 + (OFF_), nb_ + 16384 + ddA);                                  \
    }                                                                          \
    if ((VM_) == 6) VMW(6); else if ((VM_) == 3) VMW(3); else VMW(0);          \
    __builtin_amdgcn_s_barrier();                                              \
    i64x2 aw[4], bw[4];                                                        \
    _Pragma("unroll") for (int i = 0; i < 4; ++i)                              \
      aw[i] = *(const i64x2*)(cb_ + offA[i]);                                  \
    _Pragma("unroll") for (int i = 0; i < 4; ++i)                              \
      bw[i] = *(const i64x2*)(cb_ + 8192 + offB[i]);                           \
    __builtin_amdgcn_s_setprio(1);                                             \
    _Pragma("unroll") for (int ks = 0; ks < 2; ++ks)                           \
      _Pragma("unroll") for (int mi = 0; mi < 4; ++mi)                         \
        _Pragma("unroll") for (int ni = 0; ni < 4; ++ni)                       \
          acc[mi][ni] = __builtin_amdgcn_mfma_f32_16x16x32_fp8_fp8(            \
              aw[mi][ks], bw[ni][ks], acc[mi][ni], 0, 0, 0);                   \
    __builtin_amdgcn_s_setprio(0);                                             \
    __builtin_amdgcn_s_barrier();                                              \
  }

__global__ __launch_bounds__(512, 4) void k_attfeat8(
    const unsigned char* __restrict__ Mbf8,
    const unsigned char* __restrict__ bafT8,
    short* __restrict__ attf) {
  __shared__ char sm[73728];
  int wg = blockIdx.x;                       // 1056 = 8 * 132
  int wgid = (wg & 7) * 132 + (wg >> 3);     // XCD-chunked, bijective
  int bb = wgid / 132;
  int rem = wgid - bb * 132;
  int it = rem / 6, dt = rem - it * 6;       // dt fastest: A-panel reuse
  int m0 = it * 128, n0 = dt * 256;
  const unsigned char* Ab = Mbf8 + ((size_t)bb * MROW + m0) * 2816;
  const unsigned char* Bb = bafT8 + ((size_t)bb * BTROWS + n0) * 2816;

  int t = threadIdx.x, w = t >> 6, l = t & 63;
  int lr = l & 15, lg = l >> 4;
  int wr = w >> 2, wc = w & 3;

  const char* gA0; const char* gB0; const char* gB1;
  int ddA = t * 16;
  {
    int oA = t * 16;
    int rA = oA >> 6, cA = (oA & 63) ^ (((oA >> 7) & 3) << 4);
    gA0 = (const char*)Ab + (size_t)rA * 2816 + cA;
    int oB0 = t * 16;
    int rB0 = oB0 >> 6, cB0 = (oB0 & 63) ^ (((oB0 >> 7) & 3) << 4);
    gB0 = (const char*)Bb + (size_t)rB0 * 2816 + cB0;
    int oB1 = 8192 + t * 16;
    int rB1 = oB1 >> 6, cB1 = (oB1 & 63) ^ (((oB1 >> 7) & 3) << 4);
    gB1 = (const char*)Bb + (size_t)rB1 * 2816 + cB1;
  }
  int offA[4], offB[4];
#pragma unroll
  for (int i = 0; i < 4; ++i) {
    int xa = (wr * 64 + i * 16 + lr) * 64 + lg * 16;
    offA[i] = xa ^ (((xa >> 7) & 3) << 4);
    int xb = (wc * 64 + i * 16 + lr) * 64 + lg * 16;
    offB[i] = xb ^ (((xb >> 7) & 3) << 4);
  }

  f32x4 acc[4][4];
  const f32x4 fz = {0.f, 0.f, 0.f, 0.f};
#pragma unroll
  for (int mi = 0; mi < 4; ++mi)
#pragma unroll
    for (int ni = 0; ni < 4; ++ni) acc[mi][ni] = fz;

  gld16(gA0, sm + ddA);
  gld16(gB0, sm + 8192 + ddA);
  gld16(gB1, sm + 16384 + ddA);
  gld16(gA0 + 64, sm + 24576 + ddA);
  gld16(gB0 + 64, sm + 24576 + 8192 + ddA);
  gld16(gB1 + 64, sm + 24576 + 16384 + ddA);

  for (int q = 0; q < 14; ++q) {             // 44 K-tiles of 64 (K=2816)
    AF_TILE(128, 0, 2, 1, 6);
    AF_TILE(192, 1, 0, 1, 6);
    AF_TILE(256, 2, 1, 1, 6);
    gA0 += 192; gB0 += 192; gB1 += 192;
  }
  AF_TILE(0, 0, 0, 0, 3);
  AF_TILE(0, 1, 0, 0, 0);

  const float US = 1.0f / 1024.0f;
#pragma unroll
  for (int mi = 0; mi < 4; ++mi) {
#pragma unroll
    for (int rg = 0; rg < 4; ++rg) {
      int i = m0 + wr * 64 + mi * 16 + lg * 4 + rg;
      if (i < PTOT) {
        short* arow = attf + ((size_t)(bb * PTOT + i)) * DDIM;
#pragma unroll
        for (int ni = 0; ni < 4; ++ni) {
          int d = n0 + wc * 64 + ni * 16 + lr;
          if (d < DDIM) arow[d] = f2bf_rne(acc[mi][ni][rg] * US);
        }
      }
    }
  }
}

// -------- kernel 5: row softmax -> f32 M + fp8 Mbf8 (k-permuted) --------------
template<int INMODE>
__global__ __launch_bounds__(256) void k_softmax(float* __restrict__ M,
                                                 unsigned char* __restrict__ Mbf8,
                                                 const short* __restrict__ Msc) {
  __shared__ float red[8];
  int r = blockIdx.x;
  int b = r / PTOT, p = r - b * PTOT;
  float* pr = M + (size_t)r * PTOT;
  const short* ms = INMODE ? (Msc + (size_t)r * PTOT) : (const short*)nullptr;
  unsigned char* mb = Mbf8 + ((size_t)b * MROW + p) * 2816;
  int t = threadIdx.x;
  bool has2 = (t < 348 - 256);
  float v0[8], v1[8];
  float mx = -3.0e38f;
  if (INMODE == 0) {
    f32x4 a0 = *(const f32x4*)(pr + t * 8);
    f32x4 a1 = *(const f32x4*)(pr + t * 8 + 4);
#pragma unroll
    for (int e = 0; e < 4; ++e) { v0[e] = a0[e]; v0[4 + e] = a1[e]; }
  } else {
    bf16x8 a = *(const bf16x8*)(ms + t * 8);
#pragma unroll
    for (int e = 0; e < 8; ++e) v0[e] = bf2f(a[e]);
  }
#pragma unroll
  for (int e = 0; e < 8; ++e) mx = fmaxf(mx, v0[e]);
  if (has2) {
    if (INMODE == 0) {
      f32x4 b0 = *(const f32x4*)(pr + (256 + t) * 8);
      f32x4 b1 = *(const f32x4*)(pr + (256 + t) * 8 + 4);
#pragma unroll
      for (int e = 0; e < 4; ++e) { v1[e] = b0[e]; v1[4 + e] = b1[e]; }
    } else {
      bf16x8 bb = *(const bf16x8*)(ms + (256 + t) * 8);
#pragma unroll
      for (int e = 0; e < 8; ++e) v1[e] = bf2f(bb[e]);
    }
#pragma unroll
    for (int e = 0; e < 8; ++e) mx = fmaxf(mx, v1[e]);
  }
#pragma unroll
  for (int off = 32; off; off >>= 1) mx = fmaxf(mx, __shfl_xor(mx, off));
  if ((t & 63) == 0) red[t >> 6] = mx;
  __syncthreads();
  mx = fmaxf(fmaxf(red[0], red[1]), fmaxf(red[2], red[3]));
  float s = 0.f;
#pragma unroll
  for (int e = 0; e < 8; ++e) { v0[e] = __expf(v0[e] - mx); s += v0[e]; }
  if (has2) {
#pragma unroll
    for (int e = 0; e < 8; ++e) { v1[e] = __expf(v1[e] - mx); s += v1[e]; }
  }
#pragma unroll
  for (int off = 32; off; off >>= 1) s += __shfl_xor(s, off);
  if ((t & 63) == 0) red[4 + (t >> 6)] = s;
  __syncthreads();
  s = (red[4] + red[5]) + (red[6] + red[7]);
  float inv = 1.f / s;
  float invs = inv * 1024.f;
  {
    f32x4 o0, o1; unsigned long long pk = 0;
#pragma unroll
    for (int e = 0; e < 8; ++e) {
      float wv = v0[e] * inv;
      if (e < 4) o0[e] = wv; else o1[e - 4] = wv;
      pk |= (unsigned long long)f2e4m3(v0[e] * invs) << (8 * e);
    }
    *(f32x4*)(pr + t * 8) = o0;
    *(f32x4*)(pr + t * 8 + 4) = o1;
    *(unsigned long long*)(mb + kperm((uint32_t)t * 8)) = pk;
  }
  if (has2) {
    f32x4 o0, o1; unsigned long long pk = 0;
#pragma unroll
    for (int e = 0; e < 8; ++e) {
      float wv = v1[e] * inv;
      if (e < 4) o0[e] = wv; else o1[e - 4] = wv;
      pk |= (unsigned long long)f2e4m3(v1[e] * invs) << (8 * e);
    }
    *(f32x4*)(pr + (256 + t) * 8) = o0;
    *(f32x4*)(pr + (256 + t) * 8 + 4) = o1;
    *(unsigned long long*)(mb + kperm((uint32_t)(256 + t) * 8)) = pk;
  }
}

// ---- kernel 7: heads GEMM + proposal assembly (3-slot counted-vmcnt) ---------
__global__ __launch_bounds__(256) void k_head(
    const short* __restrict__ attf, const short* __restrict__ baf,
    const short* __restrict__ wbf, const float* __restrict__ bias80,
    const float* __restrict__ anch, float* __restrict__ out) {
  __shared__ char sm[27648];                 // 3 x 9216
  int r0 = blockIdx.x * 64;
  int t = threadIdx.x, w = t >> 6, lane = t & 63;
  int lr = lane & 15, lg = lane >> 4;
  int ddA = t * 16;
  const char* gA_att = (const char*)(attf + (size_t)(r0 + (t >> 2)) * DDIM) + (t & 3) * 16;
  const char* gA_baf = (const char*)(baf + (size_t)(r0 + (t >> 2)) * DDIM) + (t & 3) * 16;
  const char* gB1 = (const char*)(wbf + (size_t)(t >> 2) * KHEAD) + (t & 3) * 16;
  const char* gB2 = (const char*)(wbf + (size_t)(64 + (t >> 2)) * KHEAD) + (t & 3) * 16;
  int pAo = (w * 16 + lr) * 64 + lg * 16;    // A: row (w*16+lr), 16B
  int pBo = 4096 + lr * 64 + lg * 16;        // B: row lr (+ni*16), 16B
  f32x4 acc[5];
  const f32x4 fz = {0.f, 0.f, 0.f, 0.f};
#pragma unroll
  for (int i2 = 0; i2 < 5; ++i2) acc[i2] = fz;

#pragma unroll
  for (int s = 0; s < 2; ++s) {
    char* nb = sm + s * 9216;
    gld16(gA_att + s * 64, nb + ddA);
    gld16(gB1 + s * 64, nb + 4096 + ddA);
    if (t < 64) gld16(gB2 + s * 64, nb + 8192 + ddA);
  }

#pragma unroll
  for (int kt = 0; kt < 88; ++kt) {
    const char* cb_ = sm + (kt % 3) * 9216;
    int s = kt + 2;
    if (s < 88) {
      char* nb_ = sm + (s % 3) * 9216;
      const char* asrc = (s < 44) ? (gA_att + s * 64) : (gA_baf + (s - 44) * 64);
      gld16(asrc, nb_ + ddA);
      gld16(gB1 + s * 64, nb_ + 4096 + ddA);
      if (t < 64) gld16(gB2 + s * 64, nb_ + 8192 + ddA);
    }
    if (w == 0) { if (kt < 86) VMW(6); else if (kt == 86) VMW(3); else VMW(0); }
    else        { if (kt < 86) VMW(4); else if (kt == 86) VMW(2); else VMW(0); }
    __builtin_amdgcn_s_barrier();
    bf16x8 a = *(const bf16x8*)(cb_ + pAo);
    __builtin_amdgcn_s_setprio(1);
#pragma unroll
    for (int ni = 0; ni < 5; ++ni) {
      bf16x8 bvv = *(const bf16x8*)(cb_ + pBo + ni * 1024);
      acc[ni] = __builtin_amdgcn_mfma_f32_16x16x32_bf16(a, bvv, acc[ni], 0, 0, 0);
    }
    __builtin_amdgcn_s_setprio(0);
    __builtin_amdgcn_s_barrier();
  }

#pragma unroll
  for (int ni = 0; ni < 5; ++ni) {
#pragma unroll
    for (int rg = 0; rg < 4; ++rg) {
      int n = ni * 16 + lr;
      int i = w * 16 + lg * 4 + rg;
      int rgl = r0 + i;
      int p = rgl % PTOT;
      float v = acc[ni][rg] + bias80[n];
      if (n < 2) {
        out[(size_t)rgl * 77 + n] = v;
      } else if (n == 2) {
        out[(size_t)rgl * 77 + 2] =
            (anch[(size_t)p * 77 + 2] + 1.f / (1.f + __expf(-v))) * 0.5f;
        out[(size_t)rgl * 77 + 3] = anch[(size_t)p * 77 + 3];
      } else if (n < 76) {
        out[(size_t)rgl * 77 + n + 1] = v + anch[(size_t)p * 77 + n + 1];
      }
    }
  }
}

extern "C" void kernel_launch(void* const* d_in, const int* in_sizes, int n_in,
                              void* d_out, int out_size, void* d_ws, size_t ws_size,
                              hipStream_t stream) {
  const float* x      = (const float*)d_in[0];
  const float* conv_w = (const float*)d_in[1];
  const float* conv_b = (const float*)d_in[2];
  const float* att_w  = (const float*)d_in[3];
  const float* att_b  = (const float*)d_in[4];
  const float* cls_w  = (const float*)d_in[5];
  const float* cls_b  = (const float*)d_in[6];
  const float* so_w   = (const float*)d_in[7];
  const float* so_b   = (const float*)d_in[8];
  const float* reg_w  = (const float*)d_in[9];
  const float* reg_b  = (const float*)d_in[10];
  const float* anchors= (const float*)d_in[11];
  const int*   cut_xs = (const int*)d_in[12];
  const unsigned char* invalid = (const unsigned char*)d_in[13];

  float* out_rp = (float*)d_out;
  float* Mmat = out_rp + (size_t)ROWS * 77;
  float* feat = Mmat + (size_t)ROWS * PTOT;

  // workspace layout; base 231,858,688 B (proven), +124,010,496 for Msc (gated)
  char* wsp = (char*)d_ws;
  short* baf            = (short*)wsp;                          // 62,717,952
  unsigned char* bafT8  = (unsigned char*)(wsp + 62717952ULL);  // 34,603,008
  unsigned char* Mbf8   = (unsigned char*)(wsp + 97320960ULL);  // 63,438,848
  short* attw           = (short*)(wsp + 160759808ULL);         //  7,929,856
  short* wbf            = (short*)(wsp + 168689664ULL);         //    450,560
  float* bias80         = (float*)(wsp + 169140224ULL);         //        512
  short* attf           = (short*)(wsp + 169140736ULL);         // 62,717,952
  short* Msc            = (short*)(wsp + 231858688ULL);         // 124,010,496
  const size_t WS_FAST  = 231858688ULL + 124010496ULL;          // 355,869,184

  bool fast = (ws_size >= WS_FAST);

  k_conv<<<224, 256, 0, stream>>>(x, conv_w, conv_b, feat);
  k_prep<<<2048, 256, 0, stream>>>(att_w, cls_w, so_w, reg_w, cls_b, so_b, reg_b,
                                   attw, wbf, bias80, Mmat, Mbf8, bafT8,
                                   fast ? Msc : (short*)nullptr);
  k_gather<<<dim3(44, 24, 8), 256, 0, stream>>>(feat, cut_xs, invalid, baf, bafT8);
  if (fast) {
    k_scores<1><<<1914, 512, 0, stream>>>(baf, attw, att_b, (float*)nullptr, Msc);
    k_softmax<1><<<ROWS, 256, 0, stream>>>(Mmat, Mbf8, Msc);
  } else {
    k_scores<0><<<1914, 512, 0, stream>>>(baf, attw, att_b, Mmat, (short*)nullptr);
    k_softmax<0><<<ROWS, 256, 0, stream>>>(Mmat, Mbf8, (const short*)nullptr);
  }
  k_attfeat8<<<1056, 512, 0, stream>>>(Mbf8, bafT8, attf);
  k_head<<<348, 256, 0, stream>>>(attf, baf, wbf, bias80, anchors, out_rp);
}